// Round 3
// baseline (702.507 us; speedup 1.0000x reference)
//
#include <hip/hip_runtime.h>
#include <hip/hip_bf16.h>

// ValueNet: 7x SAGEConv(mean) + global_add_pool + MLP head.
// N=50000 nodes, E=600000 edges/set, H=128, G=64 graphs.
//
// out_i = mean_j(z_j) + bl + y_i,  z = h@Wl, y = h@Wr (linearity of mean).
// GEMM on MFMA bf16 with split precision (hi+lo planes, 3 MFMAs: hh+hl+lh).
// z,y stored bf16. h stored as hi/lo bf16 planes.
//
// R15: column-sliced L2-resident aggregation. k_agg: 4 slices x 32 cols;
//      slice = (blockIdx&7)>>1 pins each slice to an XCD pair (round-robin
//      dispatch) -> per-XCD z working set 3.2MB < 4MB L2 -> 600Kx64B gather
//      served from own-XCD L2 (34.5 TB/s agg) instead of L3. Writes prenorm
//      hi/lo + per-slice ssq partials; k_norm rescales rows in place
//      (skipped for layer 4, norm=False). Neighbor sum trees + ssq tree
//      replicate R13's rounding order exactly; norm layers add one extra
//      hi/lo resplit (~2^-17 rel).
// R14: GEMM A-staging via global_load_lds(16B), XOR-swizzled source;
//      k_scatter2 at 512 threads.
// CSR build (R12): LDS-staged bucket sort, NO per-key global atomics.

constexpr int N_NODES = 50000;
constexpr int NE      = 600000;
constexpr int H       = 128;
constexpr int NG      = 64;
constexpr int N3      = 3 * N_NODES;            // 150000

constexpr int NB   = (N3 + 1023) >> 10;          // 147 buckets (1024 keys each)
constexpr int EPB  = 2048;                       // edges per block (phase A)
constexpr int BPS  = (NE + EPB - 1) / EPB;       // 293 blocks per edge set
constexpr int CAP2 = 19456;                      // slots/bucket (exp ~15.4k padded; mult of 8)

typedef __attribute__((ext_vector_type(8))) short short8;
typedef __attribute__((ext_vector_type(4))) float f32x4;

__device__ __forceinline__ ushort f2bf(float f) {  // RNE float->bf16
    uint x = __float_as_uint(f);
    return (ushort)((x + 0x7FFFu + ((x >> 16) & 1u)) >> 16);
}
__device__ __forceinline__ float bf2f(ushort u) {
    return __uint_as_float(((uint)u) << 16);
}

// ---------------- Phase A: LDS-staged bucketize (padded, sentinel-filled) ----------------

__global__ __launch_bounds__(256) void k_bucketize(
    const int* __restrict__ e0, const int* __restrict__ e1,
    const int* __restrict__ e2, int* __restrict__ gcnt,
    int* __restrict__ rcnt, int2* __restrict__ bucket) {
    __shared__ int hist[NB];
    __shared__ int basearr[NB];
    __shared__ int cur[NB];
    __shared__ int gposs[NB];
    __shared__ int2 stage[EPB];
    __shared__ int dstoff[EPB];

    int t = threadIdx.x;
    int s = blockIdx.x / BPS;
    int w = blockIdx.x - s * BPS;
    const int* ep = (s == 0 ? e0 : (s == 1 ? e1 : e2));
    int eBase = w * EPB;
    int m = NE - eBase;
    if (m > EPB) m = EPB;

    for (int i = t; i < NB; i += 256) hist[i] = 0;
    __syncthreads();

    // pass 1: read edges into regs, LDS histogram
    int myk[EPB / 256], mys[EPB / 256];
#pragma unroll
    for (int k = 0; k < EPB / 256; ++k) {
        int i = t + 256 * k;
        if (i < m) {
            int d   = ep[NE + eBase + i];
            int src = ep[eBase + i];
            int key = s * N_NODES + d;
            myk[k] = key; mys[k] = src;
            atomicAdd(&hist[key >> 10], 1);
        } else {
            myk[k] = -1;
        }
    }
    __syncthreads();

    if (t == 0) {  // serial scan over 147 entries (cheap)
        int run = 0;
        for (int b = 0; b < NB; ++b) { basearr[b] = run; run += hist[b]; }
    }
    __syncthreads();

    if (t < NB) {  // padded reserve: ONE atomic per (block,bucket); runs 64B-aligned
        int h = hist[t];
        int p = (h + 7) & ~7;
        gposs[t] = p ? atomicAdd(&gcnt[t], p) : 0;
        if (h) atomicAdd(&rcnt[t], h);
        cur[t] = 0;
    }
    __syncthreads();

    // pass 2: scatter into LDS stage in bucket order; record dense dst offsets
#pragma unroll
    for (int k = 0; k < EPB / 256; ++k) {
        if (myk[k] >= 0) {
            int b  = myk[k] >> 10;
            int sl = atomicAdd(&cur[b], 1);
            int p  = basearr[b] + sl;
            stage[p]  = make_int2(myk[k], mys[k]);
            dstoff[p] = b * CAP2 + gposs[b] + sl;
        }
    }
    __syncthreads();

    // copyout: consecutive stage slots within a run -> consecutive global addrs
    for (int i = t; i < m; i += 256) bucket[dstoff[i]] = stage[i];
    // sentinel-fill the pad slots (<=7 per (block,bucket), same lines as runs)
    for (int i = t; i < NB * 8; i += 256) {
        int b = i >> 3, j = i & 7;
        int h = hist[b];
        int p = (h + 7) & ~7;
        if (h + j < p)
            bucket[(size_t)b * CAP2 + gposs[b] + h + j] = make_int2(-1, 0);
    }
}

// ---------------- Phase B: per-bucket hist + scan -> ptr slice + adj scatter ----------------

__global__ __launch_bounds__(512) void k_scatter2(const int2* __restrict__ bucket,
                                                  const int* __restrict__ gcnt,
                                                  const int* __restrict__ rcnt,
                                                  int* __restrict__ ptr,
                                                  int* __restrict__ adj) {
    int b = blockIdx.x;           // 0..NB-1
    int base = b << 10;
    int nk = N3 - base;
    if (nk > 1024) nk = 1024;
    __shared__ int lh[1024];
    __shared__ int lsum[512];
    __shared__ int lfill[1024];
    __shared__ int bb;
    int t = threadIdx.x;

    // exclusive prefix of real bucket totals -> bb (value at index b only)
    int rv = (t < NB) ? rcnt[t] : 0;
    lsum[t] = rv;
    __syncthreads();
    for (int off = 1; off < 512; off <<= 1) {
        int u = (t >= off) ? lsum[t - off] : 0;
        __syncthreads();
        if (t >= off) lsum[t] += u;
        __syncthreads();
    }
    if (t == b) bb = lsum[t] - rv;
    if (b == 0 && t == 0) ptr[N3] = 3 * NE;
    for (int i = t; i < 1024; i += 512) lh[i] = 0;
    __syncthreads();

    int c = gcnt[b];              // padded slot count actually used
    const int2* seg = bucket + (size_t)b * CAP2;
    for (int i = t; i < c; i += 512) {
        int k = seg[i].x;
        if (k >= 0) atomicAdd(&lh[k - base], 1);
    }
    __syncthreads();
    // exclusive 1024-scan: 2 seq per thread + 512 Hillis-Steele
    int v0 = lh[t * 2], v1 = lh[t * 2 + 1];
    int ts = v0 + v1;
    lsum[t] = ts;
    __syncthreads();
    for (int off = 1; off < 512; off <<= 1) {
        int u = (t >= off) ? lsum[t - off] : 0;
        __syncthreads();
        if (t >= off) lsum[t] += u;
        __syncthreads();
    }
    int ex = lsum[t] - ts + bb;
    int e0 = ex, e1 = ex + v0;
    if (t * 2     < nk) { ptr[base + t * 2]     = e0; lfill[t * 2]     = e0; }
    if (t * 2 + 1 < nk) { ptr[base + t * 2 + 1] = e1; lfill[t * 2 + 1] = e1; }
    __syncthreads();
    for (int i = t; i < c; i += 512) {
        int2 ed = seg[i];
        if (ed.x >= 0) {
            int pos = atomicAdd(&lfill[ed.x - base], 1);
            adj[pos] = ed.y;
        }
    }
}

// ---------------- split x (fp32) -> hi/lo bf16 planes (+ zero gbuf/gcnt/rcnt) ----------------

__global__ void k_split(const float* __restrict__ x, ushort* __restrict__ hi,
                        ushort* __restrict__ lo, int* __restrict__ zmem) {
    int tid = blockIdx.x * 256 + threadIdx.x;
    if (tid < NG * H + 2 * NB) zmem[tid] = 0;   // gbuf + gcnt + rcnt (stream-ordered)
    size_t i = (size_t)tid * 4;
    if (i >= (size_t)N_NODES * H) return;
    float4 v = *(const float4*)(x + i);
    ushort4 h, l;
    h.x = f2bf(v.x); l.x = f2bf(v.x - bf2f(h.x));
    h.y = f2bf(v.y); l.y = f2bf(v.y - bf2f(h.y));
    h.z = f2bf(v.z); l.z = f2bf(v.z - bf2f(h.z));
    h.w = f2bf(v.w); l.w = f2bf(v.w - bf2f(h.w));
    *(ushort4*)(hi + i) = h;
    *(ushort4*)(lo + i) = l;
}

// ---------------- weight pre-scatter into MFMA fragment order (all 5 convs) ----------------
// B = [Wl | Wr]  (128 k x 256 n). k = q*32 + g*8 + j -> ((q*4+g)*256 + n)*8 + j.

__global__ void k_wsplit5(const float* W0l, const float* W0r, const float* W1l,
                          const float* W1r, const float* W2l, const float* W2r,
                          const float* W3l, const float* W3r, const float* W4l,
                          const float* W4r, ushort* __restrict__ Bpk) {
    int idx = blockIdx.x * 256 + threadIdx.x;  // 0..5*32768-1
    if (idx >= 5 * 32768) return;
    int c = idx >> 15, r = idx & 32767;
    const float* Wl = (c == 0 ? W0l : c == 1 ? W1l : c == 2 ? W2l : c == 3 ? W3l : W4l);
    const float* Wr = (c == 0 ? W0r : c == 1 ? W1r : c == 2 ? W2r : c == 3 ? W3r : W4r);
    int n = r & 255, k = r >> 8;
    float w = (n < H) ? Wl[k * H + n] : Wr[k * H + (n - H)];
    int q = k >> 5, g = (k >> 3) & 3, j = k & 7;
    int off = ((q * 4 + g) * 256 + n) * 8 + j;
    ushort h = f2bf(w);
    ushort* bh = Bpk + (size_t)c * 65536;
    bh[off]         = h;
    bh[32768 + off] = f2bf(w - bf2f(h));
}

// ---------------- MFMA GEMM: (z,y) = (Ahi+Alo) @ (Bhi+Blo) ----------------
// R14 staging: global_load_lds(16B), linear LDS dest, XOR-swizzled source.

__global__ __launch_bounds__(256) void k_gemm_mfma(
    const ushort* __restrict__ Ahi, const ushort* __restrict__ Alo,
    const ushort* __restrict__ Bh, const ushort* __restrict__ Bl,
    ushort* __restrict__ z, ushort* __restrict__ yb) {
    __shared__ ushort AshF[2 * 64 * 128];   // 32 KB
    int t = threadIdx.x;
    int rowBase = blockIdx.x * 64;
    {
        int wslot = t & ~63;                 // wave-uniform slot base
        int lane  = t & 63;
#pragma unroll
        for (int i = 0; i < 8; ++i) {
            int sbase = i * 256 + wslot;     // wave's first slot this round
            int S     = sbase + lane;        // this lane's slot
            int plane = S >> 10;
            int row   = (S >> 4) & 63;
            int pc    = S & 15;
            int grow  = rowBase + row;
            if (grow > N_NODES - 1) grow = N_NODES - 1;
            const ushort* Ap  = plane ? Alo : Ahi;
            const ushort* src = Ap + (size_t)grow * H + ((pc ^ (row & 15)) << 3);
            ushort* ldst = AshF + (size_t)sbase * 8;   // wave-uniform; HW adds lane*16B
            __builtin_amdgcn_global_load_lds(
                (const __attribute__((address_space(1))) void*)src,
                (__attribute__((address_space(3))) void*)ldst, 16, 0, 0);
        }
    }
    __syncthreads();

    int wave = t >> 6, lane = t & 63;
    int m16 = lane & 15, q4 = lane >> 4;
    int n0 = wave * 64;

    f32x4 acc[4][4];
#pragma unroll
    for (int r = 0; r < 4; ++r)
#pragma unroll
        for (int c = 0; c < 4; ++c) {
            acc[r][c][0] = 0.f; acc[r][c][1] = 0.f;
            acc[r][c][2] = 0.f; acc[r][c][3] = 0.f;
        }

    for (int q = 0; q < 4; ++q) {
        short8 bh_[4], bl_[4], ah_[4], al_[4];
#pragma unroll
        for (int c = 0; c < 4; ++c) {
            int boff = ((q * 4 + q4) * 256 + n0 + c * 16 + m16) * 8;
            bh_[c] = *(const short8*)(Bh + boff);
            bl_[c] = *(const short8*)(Bl + boff);
        }
#pragma unroll
        for (int r = 0; r < 4; ++r) {
            int roff = ((r * 16 + m16) << 7) + (((q * 4 + q4) ^ m16) << 3);
            ah_[r] = *(const short8*)&AshF[roff];
            al_[r] = *(const short8*)&AshF[8192 + roff];
        }
#pragma unroll
        for (int r = 0; r < 4; ++r)
#pragma unroll
            for (int c = 0; c < 4; ++c) {
                acc[r][c] = __builtin_amdgcn_mfma_f32_16x16x32_bf16(
                    ah_[r], bh_[c], acc[r][c], 0, 0, 0);
                acc[r][c] = __builtin_amdgcn_mfma_f32_16x16x32_bf16(
                    ah_[r], bl_[c], acc[r][c], 0, 0, 0);
                acc[r][c] = __builtin_amdgcn_mfma_f32_16x16x32_bf16(
                    al_[r], bh_[c], acc[r][c], 0, 0, 0);
            }
    }

    // C/D layout: col=lane&15, row=(lane>>4)*4+reg (m89-verified)
#pragma unroll
    for (int r = 0; r < 4; ++r)
#pragma unroll
        for (int c = 0; c < 4; ++c) {
            int col = n0 + c * 16 + m16;
            ushort* op = (col < H) ? (z + col) : (yb + (col - H));
#pragma unroll
            for (int j = 0; j < 4; ++j) {
                int gr = rowBase + r * 16 + q4 * 4 + j;
                if (gr < N_NODES) op[(size_t)gr * H] = f2bf(acc[r][c][j]);
            }
        }
}

// ---------------- R15: column-sliced aggregation (L2-resident gather) ----------------
// slice = (blockIdx&7)>>1 -> round-robin block->XCD dispatch pins each slice
// (3.2MB of z cols) to an XCD pair's L2. 4 lanes/node/slice, 64B gathers.
// Writes PRE-norm hi/lo + per-slice ssq partial; k_norm rescales in place.

__global__ __launch_bounds__(256) void k_agg(
    const ushort* __restrict__ z, const ushort* __restrict__ yb,
    const int* __restrict__ ptr, const int* __restrict__ adj,
    const float* __restrict__ bl,
    ushort* __restrict__ hhi, ushort* __restrict__ hlo,
    float* __restrict__ ssq) {
    int bid = blockIdx.x;
    int g = bid >> 3, r = bid & 7;
    int slice   = r >> 1;              // 0..3
    int nodeblk = g * 2 + (r & 1);     // 0..781
    int t = threadIdx.x;
    int grp = t >> 2;                  // 0..63
    int l = t & 3;
    int node = nodeblk * 64 + grp;
    if (node >= N_NODES) return;
    int beg = ptr[node], end = ptr[node + 1];
    int deg = end - beg;
    int lb = (t & 63) & ~3;            // group's base lane within the wave
    const ushort* zsl = z + slice * 32 + l * 8;
    float a[8];
#pragma unroll
    for (int k = 0; k < 8; ++k) a[k] = 0.f;

    for (int base = 0; base < deg; base += 8) {
        int m = deg - base;
        if (m > 8) m = 8;
        int ix0 = 0, ix1 = 0;          // lane l holds adj[base+2l], adj[base+2l+1]
        if (l * 2 < m)     ix0 = __builtin_nontemporal_load(adj + beg + base + l * 2);
        if (l * 2 + 1 < m) ix1 = __builtin_nontemporal_load(adj + beg + base + l * 2 + 1);
        int n0 = __shfl(ix0, lb + 0, 64), n1 = __shfl(ix1, lb + 0, 64);
        int n2 = __shfl(ix0, lb + 1, 64), n3 = __shfl(ix1, lb + 1, 64);
        int n4 = __shfl(ix0, lb + 2, 64), n5 = __shfl(ix1, lb + 2, 64);
        int n6 = __shfl(ix0, lb + 3, 64), n7 = __shfl(ix1, lb + 3, 64);
        if (m == 8) {
            short8 v0 = *(const short8*)(zsl + (size_t)n0 * H);
            short8 v1 = *(const short8*)(zsl + (size_t)n1 * H);
            short8 v2 = *(const short8*)(zsl + (size_t)n2 * H);
            short8 v3 = *(const short8*)(zsl + (size_t)n3 * H);
            short8 v4 = *(const short8*)(zsl + (size_t)n4 * H);
            short8 v5 = *(const short8*)(zsl + (size_t)n5 * H);
            short8 v6 = *(const short8*)(zsl + (size_t)n6 * H);
            short8 v7 = *(const short8*)(zsl + (size_t)n7 * H);
#pragma unroll
            for (int k = 0; k < 8; ++k)
                a[k] += ((bf2f((ushort)v0[k]) + bf2f((ushort)v1[k])) +
                         (bf2f((ushort)v2[k]) + bf2f((ushort)v3[k]))) +
                        ((bf2f((ushort)v4[k]) + bf2f((ushort)v5[k])) +
                         (bf2f((ushort)v6[k]) + bf2f((ushort)v7[k])));
        } else {
            if (m >= 4) {
                short8 v0 = *(const short8*)(zsl + (size_t)n0 * H);
                short8 v1 = *(const short8*)(zsl + (size_t)n1 * H);
                short8 v2 = *(const short8*)(zsl + (size_t)n2 * H);
                short8 v3 = *(const short8*)(zsl + (size_t)n3 * H);
#pragma unroll
                for (int k = 0; k < 8; ++k)
                    a[k] += (bf2f((ushort)v0[k]) + bf2f((ushort)v1[k])) +
                            (bf2f((ushort)v2[k]) + bf2f((ushort)v3[k]));
            }
            int na = (m >= 4) ? n4 : n0;
            int nb = (m >= 4) ? n5 : n1;
            int nc = (m >= 4) ? n6 : n2;
            int rem = m & 3;
            if (rem > 0) {
                short8 v = *(const short8*)(zsl + (size_t)na * H);
#pragma unroll
                for (int k = 0; k < 8; ++k) a[k] += bf2f((ushort)v[k]);
            }
            if (rem > 1) {
                short8 v = *(const short8*)(zsl + (size_t)nb * H);
#pragma unroll
                for (int k = 0; k < 8; ++k) a[k] += bf2f((ushort)v[k]);
            }
            if (rem > 2) {
                short8 v = *(const short8*)(zsl + (size_t)nc * H);
#pragma unroll
                for (int k = 0; k < 8; ++k) a[k] += bf2f((ushort)v[k]);
            }
        }
    }

    float inv = 1.0f / (float)(deg > 1 ? deg : 1);
    size_t off = (size_t)node * H + slice * 32 + l * 8;
    short8 yv = __builtin_nontemporal_load((const short8*)(yb + off));
    float4 bva = *(const float4*)(bl + slice * 32 + l * 8);
    float4 bvb = *(const float4*)(bl + slice * 32 + l * 8 + 4);
    float vv[8];
    vv[0] = a[0] * inv + bva.x + bf2f((ushort)yv[0]);
    vv[1] = a[1] * inv + bva.y + bf2f((ushort)yv[1]);
    vv[2] = a[2] * inv + bva.z + bf2f((ushort)yv[2]);
    vv[3] = a[3] * inv + bva.w + bf2f((ushort)yv[3]);
    vv[4] = a[4] * inv + bvb.x + bf2f((ushort)yv[4]);
    vv[5] = a[5] * inv + bvb.y + bf2f((ushort)yv[5]);
    vv[6] = a[6] * inv + bvb.z + bf2f((ushort)yv[6]);
    vv[7] = a[7] * inv + bvb.w + bf2f((ushort)yv[7]);

    float ss = 0.f;
#pragma unroll
    for (int k = 0; k < 8; ++k) ss += vv[k] * vv[k];
    ss += __shfl_xor(ss, 1, 64);
    ss += __shfl_xor(ss, 2, 64);       // slice partial = (l0+l1)+(l2+l3)
    if (l == 0) ssq[slice * N_NODES + node] = ss;

    short8 ho, lo8;
#pragma unroll
    for (int k = 0; k < 8; ++k) {
        ushort hh = f2bf(vv[k]);
        ho[k]  = (short)hh;
        lo8[k] = (short)f2bf(vv[k] - bf2f(hh));
    }
    *(short8*)(hhi + off) = ho;
    *(short8*)(hlo + off) = lo8;
}

// ---------------- R15: row-rescale (F.normalize) in place ----------------

__global__ __launch_bounds__(256) void k_norm(ushort* __restrict__ hhi,
                                              ushort* __restrict__ hlo,
                                              const float* __restrict__ ssq) {
    int gtid = blockIdx.x * 256 + threadIdx.x;
    int node = gtid >> 5;
    int l = threadIdx.x & 31;
    if (node >= N_NODES) return;
    // same tree as the old 16-lane butterfly: ((s0+s1)+(s2+s3))
    float ss = (ssq[node] + ssq[N_NODES + node]) +
               (ssq[2 * N_NODES + node] + ssq[3 * N_NODES + node]);
    float s = 1.0f / fmaxf(sqrtf(ss), 1e-12f);
    size_t off = (size_t)node * H + l * 4;
    ushort4 hv = *(const ushort4*)(hhi + off);
    ushort4 lv = *(const ushort4*)(hlo + off);
    float v0 = (bf2f(hv.x) + bf2f(lv.x)) * s;
    float v1 = (bf2f(hv.y) + bf2f(lv.y)) * s;
    float v2 = (bf2f(hv.z) + bf2f(lv.z)) * s;
    float v3 = (bf2f(hv.w) + bf2f(lv.w)) * s;
    ushort4 ho, lo4;
    ho.x = f2bf(v0); lo4.x = f2bf(v0 - bf2f(ho.x));
    ho.y = f2bf(v1); lo4.y = f2bf(v1 - bf2f(ho.y));
    ho.z = f2bf(v2); lo4.z = f2bf(v2 - bf2f(ho.z));
    ho.w = f2bf(v3); lo4.w = f2bf(v3 - bf2f(ho.w));
    *(ushort4*)(hhi + off) = ho;
    *(ushort4*)(hlo + off) = lo4;
}

// ---------------- global add pool (batch sorted), h = hi + lo ----------------

constexpr int POOL_ROWS = 64;

__global__ void k_pool(const ushort* __restrict__ hhi, const ushort* __restrict__ hlo,
                       const int* __restrict__ batch, float* __restrict__ g) {
    int col = threadIdx.x;  // 0..127
    int r0 = blockIdx.x * POOL_ROWS;
    int r1 = r0 + POOL_ROWS;
    if (r1 > N_NODES) r1 = N_NODES;
    if (r0 >= N_NODES) return;
    float acc = 0.f;
    int cur = batch[r0];
    int r = r0;
    for (; r + 4 <= r1; r += 4) {
        float v0 = bf2f(hhi[(size_t)r * H + col])       + bf2f(hlo[(size_t)r * H + col]);
        float v1 = bf2f(hhi[(size_t)(r + 1) * H + col]) + bf2f(hlo[(size_t)(r + 1) * H + col]);
        float v2 = bf2f(hhi[(size_t)(r + 2) * H + col]) + bf2f(hlo[(size_t)(r + 2) * H + col]);
        float v3 = bf2f(hhi[(size_t)(r + 3) * H + col]) + bf2f(hlo[(size_t)(r + 3) * H + col]);
        int b3 = batch[r + 3];
        if (b3 == cur) {
            acc += (v0 + v1) + (v2 + v3);
        } else {
            int b0 = batch[r], b1 = batch[r + 1], b2 = batch[r + 2];
            if (b0 != cur) { atomicAdd(&g[cur * H + col], acc); acc = 0.f; cur = b0; }
            acc += v0;
            if (b1 != cur) { atomicAdd(&g[cur * H + col], acc); acc = 0.f; cur = b1; }
            acc += v1;
            if (b2 != cur) { atomicAdd(&g[cur * H + col], acc); acc = 0.f; cur = b2; }
            acc += v2;
            if (b3 != cur) { atomicAdd(&g[cur * H + col], acc); acc = 0.f; cur = b3; }
            acc += v3;
        }
    }
    for (; r < r1; ++r) {
        int b = batch[r];
        if (b != cur) { atomicAdd(&g[cur * H + col], acc); acc = 0.f; cur = b; }
        acc += bf2f(hhi[(size_t)r * H + col]) + bf2f(hlo[(size_t)r * H + col]);
    }
    atomicAdd(&g[cur * H + col], acc);
}

// ---------------- MLP head ----------------

__global__ void k_mlp(const float* __restrict__ g, const float* __restrict__ W0,
                      const float* __restrict__ b0, const float* __restrict__ W1,
                      const float* __restrict__ b1, const float* __restrict__ Wh,
                      const float* __restrict__ bh, float* __restrict__ out) {
    int gi = blockIdx.x;
    int t  = threadIdx.x;  // 0..127
    __shared__ float buf0[H];
    __shared__ float buf1[H];
    __shared__ float red[2];

    float acc = b0[t];
    for (int k = 0; k < H; ++k) acc += g[gi * H + k] * W0[k * H + t];
    buf0[t] = fmaxf(acc, 0.f);
    __syncthreads();

    acc = b1[t];
    for (int k = 0; k < H; ++k) acc += buf0[k] * W1[k * H + t];
    buf1[t] = fmaxf(acc, 0.f);
    __syncthreads();

    float p = buf1[t] * Wh[t];
    for (int m = 1; m < 64; m <<= 1) p += __shfl_xor(p, m, 64);
    if ((t & 63) == 0) red[t >> 6] = p;
    __syncthreads();
    if (t == 0) out[gi] = red[0] + red[1] + bh[0];
}

// ---------------- driver ----------------

extern "C" void kernel_launch(void* const* d_in, const int* in_sizes, int n_in,
                              void* d_out, int out_size, void* d_ws, size_t ws_size,
                              hipStream_t stream) {
    const float* x     = (const float*)d_in[0];
    const int*   eic   = (const int*)d_in[1];
    const int*   eid   = (const int*)d_in[2];
    const int*   eit   = (const int*)d_in[3];
    const int*   batch = (const int*)d_in[4];
    const float* cW[5][3];
    for (int c = 0; c < 5; ++c) {
        cW[c][0] = (const float*)d_in[5 + c * 3 + 0];  // Wl
        cW[c][1] = (const float*)d_in[5 + c * 3 + 1];  // bl
        cW[c][2] = (const float*)d_in[5 + c * 3 + 2];  // Wr
    }
    const float* l0_W = (const float*)d_in[20];
    const float* l0_b = (const float*)d_in[21];
    const float* l1_W = (const float*)d_in[22];
    const float* l1_b = (const float*)d_in[23];
    const float* hd_W = (const float*)d_in[24];
    const float* hd_b = (const float*)d_in[25];
    float* outp = (float*)d_out;

    const size_t NH = (size_t)N_NODES * H;
    ushort* Ahi = (ushort*)d_ws;
    ushort* Alo = Ahi + NH;
    ushort* zb  = Alo + NH;
    ushort* yb  = zb + NH;
    ushort* Bpk = yb + NH;                     // 5 convs x 2 planes x 32768
    float*  gbuf = (float*)(Bpk + 5 * 2 * 32768);
    int* gcnt = (int*)(gbuf + (size_t)NG * H);     // zeroed by k_split
    int* rcnt = gcnt + NB;                         // zeroed by k_split
    int* ptr_all = rcnt + NB;                      // N3+1 ints (persistent)
    int* adj_all = ptr_all + (N3 + 1);             // 3*NE ints (persistent)
    float* ssq   = (float*)(adj_all + 3 * NE);     // 4*N floats (0.8 MB)
    // CSR-build scratch inside zb+yb (dead until first gemm, stream-ordered):
    //   bucket[NB*CAP2 int2] (64B-aligned at zb)  = 22.88 MB < zb+yb (25.6MB)
    int2* bucket = (int2*)zb;

    dim3 b256(256);

    // weight pre-scatter + x split (also zeroes gbuf/gcnt/rcnt)
    k_wsplit5<<<dim3(640), b256, 0, stream>>>(cW[0][0], cW[0][2], cW[1][0], cW[1][2],
                                              cW[2][0], cW[2][2], cW[3][0], cW[3][2],
                                              cW[4][0], cW[4][2], Bpk);
    k_split<<<dim3((int)(NH / 1024)), b256, 0, stream>>>(x, Ahi, Alo, (int*)gbuf);

    // CSR build: bucketize -> per-bucket (total-scan + ptr + scatter)
    k_bucketize<<<dim3(3 * BPS), b256, 0, stream>>>(eic, eid, eit, gcnt, rcnt, bucket);
    k_scatter2<<<dim3(NB), dim3(512), 0, stream>>>(bucket, gcnt, rcnt, ptr_all, adj_all);

    const int L_set[7]  = {1, 0, 0, 2, 1, 0, 0};
    const int L_conv[7] = {0, 1, 1, 2, 3, 4, 4};
    const int L_norm[7] = {1, 1, 1, 0, 1, 1, 1};

    dim3 gAgg(3128);                         // 4 slices x 782 node-blocks (8-aligned)
    dim3 gNorm((N_NODES * 32 + 255) / 256);  // 6250
    dim3 gGemm((N_NODES + 63) / 64);         // 782

    for (int L = 0; L < 7; ++L) {
        int s = L_set[L], c = L_conv[L];
        const ushort* Bh = Bpk + (size_t)c * 65536;
        const ushort* Bl = Bh + 32768;
        k_gemm_mfma<<<gGemm, b256, 0, stream>>>(Ahi, Alo, Bh, Bl, zb, yb);
        k_agg<<<gAgg, b256, 0, stream>>>(zb, yb, ptr_all + s * N_NODES, adj_all,
                                         cW[c][1], Ahi, Alo, ssq);
        if (L_norm[L])
            k_norm<<<gNorm, b256, 0, stream>>>(Ahi, Alo, ssq);
    }

    k_pool<<<dim3((N_NODES + POOL_ROWS - 1) / POOL_ROWS), dim3(H), 0, stream>>>(
        Ahi, Alo, batch, gbuf);
    k_mlp<<<dim3(NG), dim3(H), 0, stream>>>(gbuf, l0_W, l0_b, l1_W, l1_b, hd_W, hd_b,
                                            outp);
}

// Round 4
// 669.423 us; speedup vs baseline: 1.0494x; 1.0494x over previous
//
#include <hip/hip_runtime.h>
#include <hip/hip_bf16.h>

// ValueNet: 7x SAGEConv(mean) + global_add_pool + MLP head.
// N=50000 nodes, E=600000 edges/set, H=128, G=64 graphs.
//
// out_i = mean_j(z_j) + bl + y_i,  z = h@Wl, y = h@Wr (linearity of mean).
// GEMM on MFMA bf16 with split precision (hi+lo planes, 3 MFMAs: hh+hl+lh).
// z,y stored bf16. h stored as hi/lo bf16 planes.
//
// R16: z and y in 4 COLUMN-PLANE arrays [4][N][32] (written by GEMM epilogue).
//      R15's slicing failed because a 128B line spanned two slices in the
//      row-major layout (per-XCD footprint 6.4MB > 4MB L2 -> thrash; FETCH
//      stayed 95MB). Planes make slice lines slice-pure: 3.2MB/XCD.
//      slice = bid&3 pins each slice to XCDs {s,s+4} under round-robin
//      block->XCD dispatch. k_agg writes prenorm hi/lo + per-slice ssq;
//      k_norm rescales rows in place (skipped for layer 4, norm=False).
// R14: GEMM A-staging via global_load_lds(16B), XOR-swizzled source;
//      k_scatter2 at 512 threads.
// CSR build (R12): LDS-staged bucket sort, NO per-key global atomics.

constexpr int N_NODES = 50000;
constexpr int NE      = 600000;
constexpr int H       = 128;
constexpr int NG      = 64;
constexpr int N3      = 3 * N_NODES;            // 150000

constexpr int NB   = (N3 + 1023) >> 10;          // 147 buckets (1024 keys each)
constexpr int EPB  = 2048;                       // edges per block (phase A)
constexpr int BPS  = (NE + EPB - 1) / EPB;       // 293 blocks per edge set
constexpr int CAP2 = 19456;                      // slots/bucket (exp ~15.4k padded; mult of 8)

typedef __attribute__((ext_vector_type(8))) short short8;
typedef __attribute__((ext_vector_type(4))) float f32x4;

__device__ __forceinline__ ushort f2bf(float f) {  // RNE float->bf16
    uint x = __float_as_uint(f);
    return (ushort)((x + 0x7FFFu + ((x >> 16) & 1u)) >> 16);
}
__device__ __forceinline__ float bf2f(ushort u) {
    return __uint_as_float(((uint)u) << 16);
}

// ---------------- Phase A: LDS-staged bucketize (padded, sentinel-filled) ----------------

__global__ __launch_bounds__(256) void k_bucketize(
    const int* __restrict__ e0, const int* __restrict__ e1,
    const int* __restrict__ e2, int* __restrict__ gcnt,
    int* __restrict__ rcnt, int2* __restrict__ bucket) {
    __shared__ int hist[NB];
    __shared__ int basearr[NB];
    __shared__ int cur[NB];
    __shared__ int gposs[NB];
    __shared__ int2 stage[EPB];
    __shared__ int dstoff[EPB];

    int t = threadIdx.x;
    int s = blockIdx.x / BPS;
    int w = blockIdx.x - s * BPS;
    const int* ep = (s == 0 ? e0 : (s == 1 ? e1 : e2));
    int eBase = w * EPB;
    int m = NE - eBase;
    if (m > EPB) m = EPB;

    for (int i = t; i < NB; i += 256) hist[i] = 0;
    __syncthreads();

    // pass 1: read edges into regs, LDS histogram
    int myk[EPB / 256], mys[EPB / 256];
#pragma unroll
    for (int k = 0; k < EPB / 256; ++k) {
        int i = t + 256 * k;
        if (i < m) {
            int d   = ep[NE + eBase + i];
            int src = ep[eBase + i];
            int key = s * N_NODES + d;
            myk[k] = key; mys[k] = src;
            atomicAdd(&hist[key >> 10], 1);
        } else {
            myk[k] = -1;
        }
    }
    __syncthreads();

    if (t == 0) {  // serial scan over 147 entries (cheap)
        int run = 0;
        for (int b = 0; b < NB; ++b) { basearr[b] = run; run += hist[b]; }
    }
    __syncthreads();

    if (t < NB) {  // padded reserve: ONE atomic per (block,bucket); runs 64B-aligned
        int h = hist[t];
        int p = (h + 7) & ~7;
        gposs[t] = p ? atomicAdd(&gcnt[t], p) : 0;
        if (h) atomicAdd(&rcnt[t], h);
        cur[t] = 0;
    }
    __syncthreads();

    // pass 2: scatter into LDS stage in bucket order; record dense dst offsets
#pragma unroll
    for (int k = 0; k < EPB / 256; ++k) {
        if (myk[k] >= 0) {
            int b  = myk[k] >> 10;
            int sl = atomicAdd(&cur[b], 1);
            int p  = basearr[b] + sl;
            stage[p]  = make_int2(myk[k], mys[k]);
            dstoff[p] = b * CAP2 + gposs[b] + sl;
        }
    }
    __syncthreads();

    // copyout: consecutive stage slots within a run -> consecutive global addrs
    for (int i = t; i < m; i += 256) bucket[dstoff[i]] = stage[i];
    // sentinel-fill the pad slots (<=7 per (block,bucket), same lines as runs)
    for (int i = t; i < NB * 8; i += 256) {
        int b = i >> 3, j = i & 7;
        int h = hist[b];
        int p = (h + 7) & ~7;
        if (h + j < p)
            bucket[(size_t)b * CAP2 + gposs[b] + h + j] = make_int2(-1, 0);
    }
}

// ---------------- Phase B: per-bucket hist + scan -> ptr slice + adj scatter ----------------

__global__ __launch_bounds__(512) void k_scatter2(const int2* __restrict__ bucket,
                                                  const int* __restrict__ gcnt,
                                                  const int* __restrict__ rcnt,
                                                  int* __restrict__ ptr,
                                                  int* __restrict__ adj) {
    int b = blockIdx.x;           // 0..NB-1
    int base = b << 10;
    int nk = N3 - base;
    if (nk > 1024) nk = 1024;
    __shared__ int lh[1024];
    __shared__ int lsum[512];
    __shared__ int lfill[1024];
    __shared__ int bb;
    int t = threadIdx.x;

    // exclusive prefix of real bucket totals -> bb (value at index b only)
    int rv = (t < NB) ? rcnt[t] : 0;
    lsum[t] = rv;
    __syncthreads();
    for (int off = 1; off < 512; off <<= 1) {
        int u = (t >= off) ? lsum[t - off] : 0;
        __syncthreads();
        if (t >= off) lsum[t] += u;
        __syncthreads();
    }
    if (t == b) bb = lsum[t] - rv;
    if (b == 0 && t == 0) ptr[N3] = 3 * NE;
    for (int i = t; i < 1024; i += 512) lh[i] = 0;
    __syncthreads();

    int c = gcnt[b];              // padded slot count actually used
    const int2* seg = bucket + (size_t)b * CAP2;
    for (int i = t; i < c; i += 512) {
        int k = seg[i].x;
        if (k >= 0) atomicAdd(&lh[k - base], 1);
    }
    __syncthreads();
    // exclusive 1024-scan: 2 seq per thread + 512 Hillis-Steele
    int v0 = lh[t * 2], v1 = lh[t * 2 + 1];
    int ts = v0 + v1;
    lsum[t] = ts;
    __syncthreads();
    for (int off = 1; off < 512; off <<= 1) {
        int u = (t >= off) ? lsum[t - off] : 0;
        __syncthreads();
        if (t >= off) lsum[t] += u;
        __syncthreads();
    }
    int ex = lsum[t] - ts + bb;
    int e0 = ex, e1 = ex + v0;
    if (t * 2     < nk) { ptr[base + t * 2]     = e0; lfill[t * 2]     = e0; }
    if (t * 2 + 1 < nk) { ptr[base + t * 2 + 1] = e1; lfill[t * 2 + 1] = e1; }
    __syncthreads();
    for (int i = t; i < c; i += 512) {
        int2 ed = seg[i];
        if (ed.x >= 0) {
            int pos = atomicAdd(&lfill[ed.x - base], 1);
            adj[pos] = ed.y;
        }
    }
}

// ---------------- split x (fp32) -> hi/lo bf16 planes (+ zero gbuf/gcnt/rcnt) ----------------

__global__ void k_split(const float* __restrict__ x, ushort* __restrict__ hi,
                        ushort* __restrict__ lo, int* __restrict__ zmem) {
    int tid = blockIdx.x * 256 + threadIdx.x;
    if (tid < NG * H + 2 * NB) zmem[tid] = 0;   // gbuf + gcnt + rcnt (stream-ordered)
    size_t i = (size_t)tid * 4;
    if (i >= (size_t)N_NODES * H) return;
    float4 v = *(const float4*)(x + i);
    ushort4 h, l;
    h.x = f2bf(v.x); l.x = f2bf(v.x - bf2f(h.x));
    h.y = f2bf(v.y); l.y = f2bf(v.y - bf2f(h.y));
    h.z = f2bf(v.z); l.z = f2bf(v.z - bf2f(h.z));
    h.w = f2bf(v.w); l.w = f2bf(v.w - bf2f(h.w));
    *(ushort4*)(hi + i) = h;
    *(ushort4*)(lo + i) = l;
}

// ---------------- weight pre-scatter into MFMA fragment order (all 5 convs) ----------------
// B = [Wl | Wr]  (128 k x 256 n). k = q*32 + g*8 + j -> ((q*4+g)*256 + n)*8 + j.

__global__ void k_wsplit5(const float* W0l, const float* W0r, const float* W1l,
                          const float* W1r, const float* W2l, const float* W2r,
                          const float* W3l, const float* W3r, const float* W4l,
                          const float* W4r, ushort* __restrict__ Bpk) {
    int idx = blockIdx.x * 256 + threadIdx.x;  // 0..5*32768-1
    if (idx >= 5 * 32768) return;
    int c = idx >> 15, r = idx & 32767;
    const float* Wl = (c == 0 ? W0l : c == 1 ? W1l : c == 2 ? W2l : c == 3 ? W3l : W4l);
    const float* Wr = (c == 0 ? W0r : c == 1 ? W1r : c == 2 ? W2r : c == 3 ? W3r : W4r);
    int n = r & 255, k = r >> 8;
    float w = (n < H) ? Wl[k * H + n] : Wr[k * H + (n - H)];
    int q = k >> 5, g = (k >> 3) & 3, j = k & 7;
    int off = ((q * 4 + g) * 256 + n) * 8 + j;
    ushort h = f2bf(w);
    ushort* bh = Bpk + (size_t)c * 65536;
    bh[off]         = h;
    bh[32768 + off] = f2bf(w - bf2f(h));
}

// ---------------- MFMA GEMM: (z,y) = (Ahi+Alo) @ (Bhi+Blo) ----------------
// R14 staging: global_load_lds(16B), linear LDS dest, XOR-swizzled source.
// R16 epilogue: z,y written into 4 column-planes [4][N][32] each.

__global__ __launch_bounds__(256) void k_gemm_mfma(
    const ushort* __restrict__ Ahi, const ushort* __restrict__ Alo,
    const ushort* __restrict__ Bh, const ushort* __restrict__ Bl,
    ushort* __restrict__ z, ushort* __restrict__ yb) {
    __shared__ ushort AshF[2 * 64 * 128];   // 32 KB
    int t = threadIdx.x;
    int rowBase = blockIdx.x * 64;
    {
        int wslot = t & ~63;                 // wave-uniform slot base
        int lane  = t & 63;
#pragma unroll
        for (int i = 0; i < 8; ++i) {
            int sbase = i * 256 + wslot;     // wave's first slot this round
            int S     = sbase + lane;        // this lane's slot
            int plane = S >> 10;
            int row   = (S >> 4) & 63;
            int pc    = S & 15;
            int grow  = rowBase + row;
            if (grow > N_NODES - 1) grow = N_NODES - 1;
            const ushort* Ap  = plane ? Alo : Ahi;
            const ushort* src = Ap + (size_t)grow * H + ((pc ^ (row & 15)) << 3);
            ushort* ldst = AshF + (size_t)sbase * 8;   // wave-uniform; HW adds lane*16B
            __builtin_amdgcn_global_load_lds(
                (const __attribute__((address_space(1))) void*)src,
                (__attribute__((address_space(3))) void*)ldst, 16, 0, 0);
        }
    }
    __syncthreads();

    int wave = t >> 6, lane = t & 63;
    int m16 = lane & 15, q4 = lane >> 4;
    int n0 = wave * 64;

    f32x4 acc[4][4];
#pragma unroll
    for (int r = 0; r < 4; ++r)
#pragma unroll
        for (int c = 0; c < 4; ++c) {
            acc[r][c][0] = 0.f; acc[r][c][1] = 0.f;
            acc[r][c][2] = 0.f; acc[r][c][3] = 0.f;
        }

    for (int q = 0; q < 4; ++q) {
        short8 bh_[4], bl_[4], ah_[4], al_[4];
#pragma unroll
        for (int c = 0; c < 4; ++c) {
            int boff = ((q * 4 + q4) * 256 + n0 + c * 16 + m16) * 8;
            bh_[c] = *(const short8*)(Bh + boff);
            bl_[c] = *(const short8*)(Bl + boff);
        }
#pragma unroll
        for (int r = 0; r < 4; ++r) {
            int roff = ((r * 16 + m16) << 7) + (((q * 4 + q4) ^ m16) << 3);
            ah_[r] = *(const short8*)&AshF[roff];
            al_[r] = *(const short8*)&AshF[8192 + roff];
        }
#pragma unroll
        for (int r = 0; r < 4; ++r)
#pragma unroll
            for (int c = 0; c < 4; ++c) {
                acc[r][c] = __builtin_amdgcn_mfma_f32_16x16x32_bf16(
                    ah_[r], bh_[c], acc[r][c], 0, 0, 0);
                acc[r][c] = __builtin_amdgcn_mfma_f32_16x16x32_bf16(
                    ah_[r], bl_[c], acc[r][c], 0, 0, 0);
                acc[r][c] = __builtin_amdgcn_mfma_f32_16x16x32_bf16(
                    al_[r], bh_[c], acc[r][c], 0, 0, 0);
            }
    }

    // C/D layout: col=lane&15, row=(lane>>4)*4+reg (m89-verified)
    // R16: plane layout [plane=col>>5][row][col&31], stride 32 per row.
#pragma unroll
    for (int r = 0; r < 4; ++r)
#pragma unroll
        for (int c = 0; c < 4; ++c) {
            int col = n0 + c * 16 + m16;
            ushort* op;
            if (col < H) {
                op = z + (size_t)(col >> 5) * N_NODES * 32 + (col & 31);
            } else {
                int cy = col - H;
                op = yb + (size_t)(cy >> 5) * N_NODES * 32 + (cy & 31);
            }
#pragma unroll
            for (int j = 0; j < 4; ++j) {
                int gr = rowBase + r * 16 + q4 * 4 + j;
                if (gr < N_NODES) op[(size_t)gr * 32] = f2bf(acc[r][c][j]);
            }
        }
}

// ---------------- R16: column-PLANE aggregation (L2-resident gather) ----------------
// slice = bid&3 -> round-robin block->XCD dispatch pins slice s to XCDs
// {s,s+4}; plane footprint 3.2MB < 4MB L2 and lines are slice-pure.
// 4 lanes/node/slice, 64B gathers. Writes PRE-norm hi/lo (row-major) +
// per-slice ssq partial; k_norm rescales rows in place.

__global__ __launch_bounds__(256) void k_agg(
    const ushort* __restrict__ z, const ushort* __restrict__ yb,
    const int* __restrict__ ptr, const int* __restrict__ adj,
    const float* __restrict__ bl,
    ushort* __restrict__ hhi, ushort* __restrict__ hlo,
    float* __restrict__ ssq) {
    int bid = blockIdx.x;
    int slice   = bid & 3;             // 0..3  (cycles fastest -> XCD-pinned)
    int nodeblk = bid >> 2;            // 0..781
    int t = threadIdx.x;
    int grp = t >> 2;                  // 0..63
    int l = t & 3;
    int node = nodeblk * 64 + grp;
    if (node >= N_NODES) return;
    int beg = ptr[node], end = ptr[node + 1];
    int deg = end - beg;
    int lb = (t & 63) & ~3;            // group's base lane within the wave
    const ushort* zsl = z + (size_t)slice * N_NODES * 32 + l * 8;
    float a[8];
#pragma unroll
    for (int k = 0; k < 8; ++k) a[k] = 0.f;

    for (int base = 0; base < deg; base += 8) {
        int m = deg - base;
        if (m > 8) m = 8;
        int ix0 = 0, ix1 = 0;          // lane l holds adj[base+2l], adj[base+2l+1]
        if (l * 2 < m)     ix0 = __builtin_nontemporal_load(adj + beg + base + l * 2);
        if (l * 2 + 1 < m) ix1 = __builtin_nontemporal_load(adj + beg + base + l * 2 + 1);
        int n0 = __shfl(ix0, lb + 0, 64), n1 = __shfl(ix1, lb + 0, 64);
        int n2 = __shfl(ix0, lb + 1, 64), n3 = __shfl(ix1, lb + 1, 64);
        int n4 = __shfl(ix0, lb + 2, 64), n5 = __shfl(ix1, lb + 2, 64);
        int n6 = __shfl(ix0, lb + 3, 64), n7 = __shfl(ix1, lb + 3, 64);
        if (m == 8) {
            short8 v0 = *(const short8*)(zsl + (size_t)n0 * 32);
            short8 v1 = *(const short8*)(zsl + (size_t)n1 * 32);
            short8 v2 = *(const short8*)(zsl + (size_t)n2 * 32);
            short8 v3 = *(const short8*)(zsl + (size_t)n3 * 32);
            short8 v4 = *(const short8*)(zsl + (size_t)n4 * 32);
            short8 v5 = *(const short8*)(zsl + (size_t)n5 * 32);
            short8 v6 = *(const short8*)(zsl + (size_t)n6 * 32);
            short8 v7 = *(const short8*)(zsl + (size_t)n7 * 32);
#pragma unroll
            for (int k = 0; k < 8; ++k)
                a[k] += ((bf2f((ushort)v0[k]) + bf2f((ushort)v1[k])) +
                         (bf2f((ushort)v2[k]) + bf2f((ushort)v3[k]))) +
                        ((bf2f((ushort)v4[k]) + bf2f((ushort)v5[k])) +
                         (bf2f((ushort)v6[k]) + bf2f((ushort)v7[k])));
        } else {
            if (m >= 4) {
                short8 v0 = *(const short8*)(zsl + (size_t)n0 * 32);
                short8 v1 = *(const short8*)(zsl + (size_t)n1 * 32);
                short8 v2 = *(const short8*)(zsl + (size_t)n2 * 32);
                short8 v3 = *(const short8*)(zsl + (size_t)n3 * 32);
#pragma unroll
                for (int k = 0; k < 8; ++k)
                    a[k] += (bf2f((ushort)v0[k]) + bf2f((ushort)v1[k])) +
                            (bf2f((ushort)v2[k]) + bf2f((ushort)v3[k]));
            }
            int na = (m >= 4) ? n4 : n0;
            int nb = (m >= 4) ? n5 : n1;
            int nc = (m >= 4) ? n6 : n2;
            int rem = m & 3;
            if (rem > 0) {
                short8 v = *(const short8*)(zsl + (size_t)na * 32);
#pragma unroll
                for (int k = 0; k < 8; ++k) a[k] += bf2f((ushort)v[k]);
            }
            if (rem > 1) {
                short8 v = *(const short8*)(zsl + (size_t)nb * 32);
#pragma unroll
                for (int k = 0; k < 8; ++k) a[k] += bf2f((ushort)v[k]);
            }
            if (rem > 2) {
                short8 v = *(const short8*)(zsl + (size_t)nc * 32);
#pragma unroll
                for (int k = 0; k < 8; ++k) a[k] += bf2f((ushort)v[k]);
            }
        }
    }

    float inv = 1.0f / (float)(deg > 1 ? deg : 1);
    short8 yv = __builtin_nontemporal_load(
        (const short8*)(yb + (size_t)slice * N_NODES * 32 + (size_t)node * 32 + l * 8));
    float4 bva = *(const float4*)(bl + slice * 32 + l * 8);
    float4 bvb = *(const float4*)(bl + slice * 32 + l * 8 + 4);
    float vv[8];
    vv[0] = a[0] * inv + bva.x + bf2f((ushort)yv[0]);
    vv[1] = a[1] * inv + bva.y + bf2f((ushort)yv[1]);
    vv[2] = a[2] * inv + bva.z + bf2f((ushort)yv[2]);
    vv[3] = a[3] * inv + bva.w + bf2f((ushort)yv[3]);
    vv[4] = a[4] * inv + bvb.x + bf2f((ushort)yv[4]);
    vv[5] = a[5] * inv + bvb.y + bf2f((ushort)yv[5]);
    vv[6] = a[6] * inv + bvb.z + bf2f((ushort)yv[6]);
    vv[7] = a[7] * inv + bvb.w + bf2f((ushort)yv[7]);

    float ss = 0.f;
#pragma unroll
    for (int k = 0; k < 8; ++k) ss += vv[k] * vv[k];
    ss += __shfl_xor(ss, 1, 64);
    ss += __shfl_xor(ss, 2, 64);       // slice partial = (l0+l1)+(l2+l3)
    if (l == 0) ssq[slice * N_NODES + node] = ss;

    short8 ho, lo8;
#pragma unroll
    for (int k = 0; k < 8; ++k) {
        ushort hh = f2bf(vv[k]);
        ho[k]  = (short)hh;
        lo8[k] = (short)f2bf(vv[k] - bf2f(hh));
    }
    size_t off = (size_t)node * H + slice * 32 + l * 8;
    *(short8*)(hhi + off) = ho;
    *(short8*)(hlo + off) = lo8;
}

// ---------------- R15: row-rescale (F.normalize) in place ----------------

__global__ __launch_bounds__(256) void k_norm(ushort* __restrict__ hhi,
                                              ushort* __restrict__ hlo,
                                              const float* __restrict__ ssq) {
    int gtid = blockIdx.x * 256 + threadIdx.x;
    int node = gtid >> 5;
    int l = threadIdx.x & 31;
    if (node >= N_NODES) return;
    // same tree as the old 16-lane butterfly: ((s0+s1)+(s2+s3))
    float ss = (ssq[node] + ssq[N_NODES + node]) +
               (ssq[2 * N_NODES + node] + ssq[3 * N_NODES + node]);
    float s = 1.0f / fmaxf(sqrtf(ss), 1e-12f);
    size_t off = (size_t)node * H + l * 4;
    ushort4 hv = *(const ushort4*)(hhi + off);
    ushort4 lv = *(const ushort4*)(hlo + off);
    float v0 = (bf2f(hv.x) + bf2f(lv.x)) * s;
    float v1 = (bf2f(hv.y) + bf2f(lv.y)) * s;
    float v2 = (bf2f(hv.z) + bf2f(lv.z)) * s;
    float v3 = (bf2f(hv.w) + bf2f(lv.w)) * s;
    ushort4 ho, lo4;
    ho.x = f2bf(v0); lo4.x = f2bf(v0 - bf2f(ho.x));
    ho.y = f2bf(v1); lo4.y = f2bf(v1 - bf2f(ho.y));
    ho.z = f2bf(v2); lo4.z = f2bf(v2 - bf2f(ho.z));
    ho.w = f2bf(v3); lo4.w = f2bf(v3 - bf2f(ho.w));
    *(ushort4*)(hhi + off) = ho;
    *(ushort4*)(hlo + off) = lo4;
}

// ---------------- global add pool (batch sorted), h = hi + lo ----------------

constexpr int POOL_ROWS = 64;

__global__ void k_pool(const ushort* __restrict__ hhi, const ushort* __restrict__ hlo,
                       const int* __restrict__ batch, float* __restrict__ g) {
    int col = threadIdx.x;  // 0..127
    int r0 = blockIdx.x * POOL_ROWS;
    int r1 = r0 + POOL_ROWS;
    if (r1 > N_NODES) r1 = N_NODES;
    if (r0 >= N_NODES) return;
    float acc = 0.f;
    int cur = batch[r0];
    int r = r0;
    for (; r + 4 <= r1; r += 4) {
        float v0 = bf2f(hhi[(size_t)r * H + col])       + bf2f(hlo[(size_t)r * H + col]);
        float v1 = bf2f(hhi[(size_t)(r + 1) * H + col]) + bf2f(hlo[(size_t)(r + 1) * H + col]);
        float v2 = bf2f(hhi[(size_t)(r + 2) * H + col]) + bf2f(hlo[(size_t)(r + 2) * H + col]);
        float v3 = bf2f(hhi[(size_t)(r + 3) * H + col]) + bf2f(hlo[(size_t)(r + 3) * H + col]);
        int b3 = batch[r + 3];
        if (b3 == cur) {
            acc += (v0 + v1) + (v2 + v3);
        } else {
            int b0 = batch[r], b1 = batch[r + 1], b2 = batch[r + 2];
            if (b0 != cur) { atomicAdd(&g[cur * H + col], acc); acc = 0.f; cur = b0; }
            acc += v0;
            if (b1 != cur) { atomicAdd(&g[cur * H + col], acc); acc = 0.f; cur = b1; }
            acc += v1;
            if (b2 != cur) { atomicAdd(&g[cur * H + col], acc); acc = 0.f; cur = b2; }
            acc += v2;
            if (b3 != cur) { atomicAdd(&g[cur * H + col], acc); acc = 0.f; cur = b3; }
            acc += v3;
        }
    }
    for (; r < r1; ++r) {
        int b = batch[r];
        if (b != cur) { atomicAdd(&g[cur * H + col], acc); acc = 0.f; cur = b; }
        acc += bf2f(hhi[(size_t)r * H + col]) + bf2f(hlo[(size_t)r * H + col]);
    }
    atomicAdd(&g[cur * H + col], acc);
}

// ---------------- MLP head ----------------

__global__ void k_mlp(const float* __restrict__ g, const float* __restrict__ W0,
                      const float* __restrict__ b0, const float* __restrict__ W1,
                      const float* __restrict__ b1, const float* __restrict__ Wh,
                      const float* __restrict__ bh, float* __restrict__ out) {
    int gi = blockIdx.x;
    int t  = threadIdx.x;  // 0..127
    __shared__ float buf0[H];
    __shared__ float buf1[H];
    __shared__ float red[2];

    float acc = b0[t];
    for (int k = 0; k < H; ++k) acc += g[gi * H + k] * W0[k * H + t];
    buf0[t] = fmaxf(acc, 0.f);
    __syncthreads();

    acc = b1[t];
    for (int k = 0; k < H; ++k) acc += buf0[k] * W1[k * H + t];
    buf1[t] = fmaxf(acc, 0.f);
    __syncthreads();

    float p = buf1[t] * Wh[t];
    for (int m = 1; m < 64; m <<= 1) p += __shfl_xor(p, m, 64);
    if ((t & 63) == 0) red[t >> 6] = p;
    __syncthreads();
    if (t == 0) out[gi] = red[0] + red[1] + bh[0];
}

// ---------------- driver ----------------

extern "C" void kernel_launch(void* const* d_in, const int* in_sizes, int n_in,
                              void* d_out, int out_size, void* d_ws, size_t ws_size,
                              hipStream_t stream) {
    const float* x     = (const float*)d_in[0];
    const int*   eic   = (const int*)d_in[1];
    const int*   eid   = (const int*)d_in[2];
    const int*   eit   = (const int*)d_in[3];
    const int*   batch = (const int*)d_in[4];
    const float* cW[5][3];
    for (int c = 0; c < 5; ++c) {
        cW[c][0] = (const float*)d_in[5 + c * 3 + 0];  // Wl
        cW[c][1] = (const float*)d_in[5 + c * 3 + 1];  // bl
        cW[c][2] = (const float*)d_in[5 + c * 3 + 2];  // Wr
    }
    const float* l0_W = (const float*)d_in[20];
    const float* l0_b = (const float*)d_in[21];
    const float* l1_W = (const float*)d_in[22];
    const float* l1_b = (const float*)d_in[23];
    const float* hd_W = (const float*)d_in[24];
    const float* hd_b = (const float*)d_in[25];
    float* outp = (float*)d_out;

    const size_t NH = (size_t)N_NODES * H;
    ushort* Ahi = (ushort*)d_ws;
    ushort* Alo = Ahi + NH;
    ushort* zb  = Alo + NH;                    // 4 planes [N][32]
    ushort* yb  = zb + NH;                     // 4 planes [N][32]
    ushort* Bpk = yb + NH;                     // 5 convs x 2 planes x 32768
    float*  gbuf = (float*)(Bpk + 5 * 2 * 32768);
    int* gcnt = (int*)(gbuf + (size_t)NG * H);     // zeroed by k_split
    int* rcnt = gcnt + NB;                         // zeroed by k_split
    int* ptr_all = rcnt + NB;                      // N3+1 ints (persistent)
    int* adj_all = ptr_all + (N3 + 1);             // 3*NE ints (persistent)
    float* ssq   = (float*)(adj_all + 3 * NE);     // 4*N floats (0.8 MB)
    // CSR-build scratch inside zb+yb (dead until first gemm, stream-ordered):
    //   bucket[NB*CAP2 int2] (64B-aligned at zb)  = 22.88 MB < zb+yb (25.6MB)
    int2* bucket = (int2*)zb;

    dim3 b256(256);

    // weight pre-scatter + x split (also zeroes gbuf/gcnt/rcnt)
    k_wsplit5<<<dim3(640), b256, 0, stream>>>(cW[0][0], cW[0][2], cW[1][0], cW[1][2],
                                              cW[2][0], cW[2][2], cW[3][0], cW[3][2],
                                              cW[4][0], cW[4][2], Bpk);
    k_split<<<dim3((int)(NH / 1024)), b256, 0, stream>>>(x, Ahi, Alo, (int*)gbuf);

    // CSR build: bucketize -> per-bucket (total-scan + ptr + scatter)
    k_bucketize<<<dim3(3 * BPS), b256, 0, stream>>>(eic, eid, eit, gcnt, rcnt, bucket);
    k_scatter2<<<dim3(NB), dim3(512), 0, stream>>>(bucket, gcnt, rcnt, ptr_all, adj_all);

    const int L_set[7]  = {1, 0, 0, 2, 1, 0, 0};
    const int L_conv[7] = {0, 1, 1, 2, 3, 4, 4};
    const int L_norm[7] = {1, 1, 1, 0, 1, 1, 1};

    dim3 gAgg(4 * 782);                      // slice = bid&3 (XCD-pinned), 782 node-blocks
    dim3 gNorm((N_NODES * 32 + 255) / 256);  // 6250
    dim3 gGemm((N_NODES + 63) / 64);         // 782

    for (int L = 0; L < 7; ++L) {
        int s = L_set[L], c = L_conv[L];
        const ushort* Bh = Bpk + (size_t)c * 65536;
        const ushort* Bl = Bh + 32768;
        k_gemm_mfma<<<gGemm, b256, 0, stream>>>(Ahi, Alo, Bh, Bl, zb, yb);
        k_agg<<<gAgg, b256, 0, stream>>>(zb, yb, ptr_all + s * N_NODES, adj_all,
                                         cW[c][1], Ahi, Alo, ssq);
        if (L_norm[L])
            k_norm<<<gNorm, b256, 0, stream>>>(Ahi, Alo, ssq);
    }

    k_pool<<<dim3((N_NODES + POOL_ROWS - 1) / POOL_ROWS), dim3(H), 0, stream>>>(
        Ahi, Alo, batch, gbuf);
    k_mlp<<<dim3(NG), dim3(H), 0, stream>>>(gbuf, l0_W, l0_b, l1_W, l1_b, hd_W, hd_b,
                                            outp);
}

// Round 5
// 516.280 us; speedup vs baseline: 1.3607x; 1.2966x over previous
//
#include <hip/hip_runtime.h>
#include <hip/hip_bf16.h>

// ValueNet: 7x SAGEConv(mean) + global_add_pool + MLP head.
// N=50000 nodes, E=600000 edges/set, H=128, G=64 graphs.
//
// out_i = mean_j(z_j) + bl + y_i,  z = h@Wl, y = h@Wr (linearity of mean).
// GEMM on MFMA bf16 with split precision (hi+lo planes, 3 MFMAs: hh+hl+lh).
// z,y stored bf16. h stored as hi/lo bf16 planes.
//
// R17: REVERT R15/R16 slicing (L2-pinning worked per FETCH 95->39MB but
//      overhead 4x ate it; agg is latency-bound, not bytes-bound).
//      k_aggnorm: issue ALL <=16 predicated gathers in flight, then
//      accumulate in the EXACT old 8/4/1 round order (bit-identical) ->
//      collapses 2-3 serialized L3-latency rounds per node to 1.
//      k_wsplit5+k_split merged into k_prep (-1 dispatch).
// R14: GEMM A-staging via global_load_lds(16B), XOR-swizzled source;
//      k_scatter2 at 512 threads.
// CSR build (R12): LDS-staged bucket sort, NO per-key global atomics.

constexpr int N_NODES = 50000;
constexpr int NE      = 600000;
constexpr int H       = 128;
constexpr int NG      = 64;
constexpr int N3      = 3 * N_NODES;            // 150000

constexpr int NB   = (N3 + 1023) >> 10;          // 147 buckets (1024 keys each)
constexpr int EPB  = 2048;                       // edges per block (phase A)
constexpr int BPS  = (NE + EPB - 1) / EPB;       // 293 blocks per edge set
constexpr int CAP2 = 19456;                      // slots/bucket (exp ~15.4k padded; mult of 8)

typedef __attribute__((ext_vector_type(8))) short short8;
typedef __attribute__((ext_vector_type(4))) float f32x4;

__device__ __forceinline__ ushort f2bf(float f) {  // RNE float->bf16
    uint x = __float_as_uint(f);
    return (ushort)((x + 0x7FFFu + ((x >> 16) & 1u)) >> 16);
}
__device__ __forceinline__ float bf2f(ushort u) {
    return __uint_as_float(((uint)u) << 16);
}

// ---------------- Phase A: LDS-staged bucketize (padded, sentinel-filled) ----------------

__global__ __launch_bounds__(256) void k_bucketize(
    const int* __restrict__ e0, const int* __restrict__ e1,
    const int* __restrict__ e2, int* __restrict__ gcnt,
    int* __restrict__ rcnt, int2* __restrict__ bucket) {
    __shared__ int hist[NB];
    __shared__ int basearr[NB];
    __shared__ int cur[NB];
    __shared__ int gposs[NB];
    __shared__ int2 stage[EPB];
    __shared__ int dstoff[EPB];

    int t = threadIdx.x;
    int s = blockIdx.x / BPS;
    int w = blockIdx.x - s * BPS;
    const int* ep = (s == 0 ? e0 : (s == 1 ? e1 : e2));
    int eBase = w * EPB;
    int m = NE - eBase;
    if (m > EPB) m = EPB;

    for (int i = t; i < NB; i += 256) hist[i] = 0;
    __syncthreads();

    // pass 1: read edges into regs, LDS histogram
    int myk[EPB / 256], mys[EPB / 256];
#pragma unroll
    for (int k = 0; k < EPB / 256; ++k) {
        int i = t + 256 * k;
        if (i < m) {
            int d   = ep[NE + eBase + i];
            int src = ep[eBase + i];
            int key = s * N_NODES + d;
            myk[k] = key; mys[k] = src;
            atomicAdd(&hist[key >> 10], 1);
        } else {
            myk[k] = -1;
        }
    }
    __syncthreads();

    if (t == 0) {  // serial scan over 147 entries (cheap)
        int run = 0;
        for (int b = 0; b < NB; ++b) { basearr[b] = run; run += hist[b]; }
    }
    __syncthreads();

    if (t < NB) {  // padded reserve: ONE atomic per (block,bucket); runs 64B-aligned
        int h = hist[t];
        int p = (h + 7) & ~7;
        gposs[t] = p ? atomicAdd(&gcnt[t], p) : 0;
        if (h) atomicAdd(&rcnt[t], h);
        cur[t] = 0;
    }
    __syncthreads();

    // pass 2: scatter into LDS stage in bucket order; record dense dst offsets
#pragma unroll
    for (int k = 0; k < EPB / 256; ++k) {
        if (myk[k] >= 0) {
            int b  = myk[k] >> 10;
            int sl = atomicAdd(&cur[b], 1);
            int p  = basearr[b] + sl;
            stage[p]  = make_int2(myk[k], mys[k]);
            dstoff[p] = b * CAP2 + gposs[b] + sl;
        }
    }
    __syncthreads();

    // copyout: consecutive stage slots within a run -> consecutive global addrs
    for (int i = t; i < m; i += 256) bucket[dstoff[i]] = stage[i];
    // sentinel-fill the pad slots (<=7 per (block,bucket), same lines as runs)
    for (int i = t; i < NB * 8; i += 256) {
        int b = i >> 3, j = i & 7;
        int h = hist[b];
        int p = (h + 7) & ~7;
        if (h + j < p)
            bucket[(size_t)b * CAP2 + gposs[b] + h + j] = make_int2(-1, 0);
    }
}

// ---------------- Phase B: per-bucket hist + scan -> ptr slice + adj scatter ----------------

__global__ __launch_bounds__(512) void k_scatter2(const int2* __restrict__ bucket,
                                                  const int* __restrict__ gcnt,
                                                  const int* __restrict__ rcnt,
                                                  int* __restrict__ ptr,
                                                  int* __restrict__ adj) {
    int b = blockIdx.x;           // 0..NB-1
    int base = b << 10;
    int nk = N3 - base;
    if (nk > 1024) nk = 1024;
    __shared__ int lh[1024];
    __shared__ int lsum[512];
    __shared__ int lfill[1024];
    __shared__ int bb;
    int t = threadIdx.x;

    // exclusive prefix of real bucket totals -> bb (value at index b only)
    int rv = (t < NB) ? rcnt[t] : 0;
    lsum[t] = rv;
    __syncthreads();
    for (int off = 1; off < 512; off <<= 1) {
        int u = (t >= off) ? lsum[t - off] : 0;
        __syncthreads();
        if (t >= off) lsum[t] += u;
        __syncthreads();
    }
    if (t == b) bb = lsum[t] - rv;
    if (b == 0 && t == 0) ptr[N3] = 3 * NE;
    for (int i = t; i < 1024; i += 512) lh[i] = 0;
    __syncthreads();

    int c = gcnt[b];              // padded slot count actually used
    const int2* seg = bucket + (size_t)b * CAP2;
    for (int i = t; i < c; i += 512) {
        int k = seg[i].x;
        if (k >= 0) atomicAdd(&lh[k - base], 1);
    }
    __syncthreads();
    // exclusive 1024-scan: 2 seq per thread + 512 Hillis-Steele
    int v0 = lh[t * 2], v1 = lh[t * 2 + 1];
    int ts = v0 + v1;
    lsum[t] = ts;
    __syncthreads();
    for (int off = 1; off < 512; off <<= 1) {
        int u = (t >= off) ? lsum[t - off] : 0;
        __syncthreads();
        if (t >= off) lsum[t] += u;
        __syncthreads();
    }
    int ex = lsum[t] - ts + bb;
    int e0 = ex, e1 = ex + v0;
    if (t * 2     < nk) { ptr[base + t * 2]     = e0; lfill[t * 2]     = e0; }
    if (t * 2 + 1 < nk) { ptr[base + t * 2 + 1] = e1; lfill[t * 2 + 1] = e1; }
    __syncthreads();
    for (int i = t; i < c; i += 512) {
        int2 ed = seg[i];
        if (ed.x >= 0) {
            int pos = atomicAdd(&lfill[ed.x - base], 1);
            adj[pos] = ed.y;
        }
    }
}

// ---------------- R17: merged prep = weight pre-scatter + x split + zeroing ----------------
// blocks [0,640): B = [Wl | Wr] scatter into MFMA fragment order (5 convs).
// blocks [640,6890): x fp32 -> hi/lo bf16 planes; first blocks also zero
// gbuf/gcnt/rcnt (stream-ordered before k_bucketize / k_pool).

__global__ void k_prep(const float* __restrict__ x, ushort* __restrict__ hi,
                       ushort* __restrict__ lo, int* __restrict__ zmem,
                       const float* W0l, const float* W0r, const float* W1l,
                       const float* W1r, const float* W2l, const float* W2r,
                       const float* W3l, const float* W3r, const float* W4l,
                       const float* W4r, ushort* __restrict__ Bpk) {
    int bid = blockIdx.x;
    int t   = threadIdx.x;
    if (bid < 640) {
        int idx = bid * 256 + t;  // 0..5*32768-1
        if (idx >= 5 * 32768) return;
        int c = idx >> 15, r = idx & 32767;
        const float* Wl = (c == 0 ? W0l : c == 1 ? W1l : c == 2 ? W2l : c == 3 ? W3l : W4l);
        const float* Wr = (c == 0 ? W0r : c == 1 ? W1r : c == 2 ? W2r : c == 3 ? W3r : W4r);
        int n = r & 255, k = r >> 8;
        float w = (n < H) ? Wl[k * H + n] : Wr[k * H + (n - H)];
        int q = k >> 5, g = (k >> 3) & 3, j = k & 7;
        int off = ((q * 4 + g) * 256 + n) * 8 + j;
        ushort h = f2bf(w);
        ushort* bh = Bpk + (size_t)c * 65536;
        bh[off]         = h;
        bh[32768 + off] = f2bf(w - bf2f(h));
        return;
    }
    int tid = (bid - 640) * 256 + t;
    if (tid < NG * H + 2 * NB) zmem[tid] = 0;   // gbuf + gcnt + rcnt
    size_t i = (size_t)tid * 4;
    if (i >= (size_t)N_NODES * H) return;
    float4 v = *(const float4*)(x + i);
    ushort4 h, l;
    h.x = f2bf(v.x); l.x = f2bf(v.x - bf2f(h.x));
    h.y = f2bf(v.y); l.y = f2bf(v.y - bf2f(h.y));
    h.z = f2bf(v.z); l.z = f2bf(v.z - bf2f(h.z));
    h.w = f2bf(v.w); l.w = f2bf(v.w - bf2f(h.w));
    *(ushort4*)(hi + i) = h;
    *(ushort4*)(lo + i) = l;
}

// ---------------- MFMA GEMM: (z,y) = (Ahi+Alo) @ (Bhi+Blo) ----------------
// R14 staging: global_load_lds(16B), linear LDS dest, XOR-swizzled source.

__global__ __launch_bounds__(256) void k_gemm_mfma(
    const ushort* __restrict__ Ahi, const ushort* __restrict__ Alo,
    const ushort* __restrict__ Bh, const ushort* __restrict__ Bl,
    ushort* __restrict__ z, ushort* __restrict__ yb) {
    __shared__ ushort AshF[2 * 64 * 128];   // 32 KB
    int t = threadIdx.x;
    int rowBase = blockIdx.x * 64;
    {
        int wslot = t & ~63;                 // wave-uniform slot base
        int lane  = t & 63;
#pragma unroll
        for (int i = 0; i < 8; ++i) {
            int sbase = i * 256 + wslot;     // wave's first slot this round
            int S     = sbase + lane;        // this lane's slot
            int plane = S >> 10;
            int row   = (S >> 4) & 63;
            int pc    = S & 15;
            int grow  = rowBase + row;
            if (grow > N_NODES - 1) grow = N_NODES - 1;
            const ushort* Ap  = plane ? Alo : Ahi;
            const ushort* src = Ap + (size_t)grow * H + ((pc ^ (row & 15)) << 3);
            ushort* ldst = AshF + (size_t)sbase * 8;   // wave-uniform; HW adds lane*16B
            __builtin_amdgcn_global_load_lds(
                (const __attribute__((address_space(1))) void*)src,
                (__attribute__((address_space(3))) void*)ldst, 16, 0, 0);
        }
    }
    __syncthreads();

    int wave = t >> 6, lane = t & 63;
    int m16 = lane & 15, q4 = lane >> 4;
    int n0 = wave * 64;

    f32x4 acc[4][4];
#pragma unroll
    for (int r = 0; r < 4; ++r)
#pragma unroll
        for (int c = 0; c < 4; ++c) {
            acc[r][c][0] = 0.f; acc[r][c][1] = 0.f;
            acc[r][c][2] = 0.f; acc[r][c][3] = 0.f;
        }

    for (int q = 0; q < 4; ++q) {
        short8 bh_[4], bl_[4], ah_[4], al_[4];
#pragma unroll
        for (int c = 0; c < 4; ++c) {
            int boff = ((q * 4 + q4) * 256 + n0 + c * 16 + m16) * 8;
            bh_[c] = *(const short8*)(Bh + boff);
            bl_[c] = *(const short8*)(Bl + boff);
        }
#pragma unroll
        for (int r = 0; r < 4; ++r) {
            int roff = ((r * 16 + m16) << 7) + (((q * 4 + q4) ^ m16) << 3);
            ah_[r] = *(const short8*)&AshF[roff];
            al_[r] = *(const short8*)&AshF[8192 + roff];
        }
#pragma unroll
        for (int r = 0; r < 4; ++r)
#pragma unroll
            for (int c = 0; c < 4; ++c) {
                acc[r][c] = __builtin_amdgcn_mfma_f32_16x16x32_bf16(
                    ah_[r], bh_[c], acc[r][c], 0, 0, 0);
                acc[r][c] = __builtin_amdgcn_mfma_f32_16x16x32_bf16(
                    ah_[r], bl_[c], acc[r][c], 0, 0, 0);
                acc[r][c] = __builtin_amdgcn_mfma_f32_16x16x32_bf16(
                    al_[r], bh_[c], acc[r][c], 0, 0, 0);
            }
    }

    // C/D layout: col=lane&15, row=(lane>>4)*4+reg (m89-verified)
#pragma unroll
    for (int r = 0; r < 4; ++r)
#pragma unroll
        for (int c = 0; c < 4; ++c) {
            int col = n0 + c * 16 + m16;
            ushort* op = (col < H) ? (z + col) : (yb + (col - H));
#pragma unroll
            for (int j = 0; j < 4; ++j) {
                int gr = rowBase + r * 16 + q4 * 4 + j;
                if (gr < N_NODES) op[(size_t)gr * H] = f2bf(acc[r][c][j]);
            }
        }
}

// ---------------- R17 gather + epilogue: 16 lanes/node, ALL loads in flight ----------------
// Issues up to 16 predicated ushort8 gathers before any accumulation, then
// replicates the R13 8/4/1 round order exactly (bit-identical results).

__global__ __launch_bounds__(256) void k_aggnorm(
    const ushort* __restrict__ z, const ushort* __restrict__ yb,
    const int* __restrict__ ptr, const int* __restrict__ adj,
    const float* __restrict__ bl,
    ushort* __restrict__ hhi, ushort* __restrict__ hlo, int norm) {
    int gtid = blockIdx.x * blockDim.x + threadIdx.x;
    int node = gtid >> 4;                  // 16 lanes per node
    int sl   = threadIdx.x & 15;           // lane covers cols [sl*8, sl*8+8)
    if (node >= N_NODES) return;
    int beg = ptr[node], end = ptr[node + 1];
    int deg = end - beg;
    const ushort* zrow = z + sl * 8;
    float a[8];
#pragma unroll
    for (int k = 0; k < 8; ++k) a[k] = 0.f;

    for (int base = 0; base < deg; base += 16) {
        int m = deg - base;
        if (m > 16) m = 16;
        int idx = (sl < m) ? adj[beg + base + sl] : 0;
        int nn[16];
#pragma unroll
        for (int jj = 0; jj < 16; ++jj) nn[jj] = __shfl(idx, jj, 16);
        short8 v[16];
#pragma unroll
        for (int jj = 0; jj < 16; ++jj) {
            if (jj < m) {
                v[jj] = *(const short8*)(zrow + (size_t)nn[jj] * H);
            } else {
                short8 zz = {0, 0, 0, 0, 0, 0, 0, 0};
                v[jj] = zz;
            }
        }
        // ---- accumulation: EXACT replication of old 8/4/1 rounds ----
        if (m >= 8) {
#pragma unroll
            for (int k = 0; k < 8; ++k)
                a[k] += ((bf2f((ushort)v[0][k]) + bf2f((ushort)v[1][k])) +
                         (bf2f((ushort)v[2][k]) + bf2f((ushort)v[3][k]))) +
                        ((bf2f((ushort)v[4][k]) + bf2f((ushort)v[5][k])) +
                         (bf2f((ushort)v[6][k]) + bf2f((ushort)v[7][k])));
            if (m == 16) {
#pragma unroll
                for (int k = 0; k < 8; ++k)
                    a[k] += ((bf2f((ushort)v[8][k]) + bf2f((ushort)v[9][k])) +
                             (bf2f((ushort)v[10][k]) + bf2f((ushort)v[11][k]))) +
                            ((bf2f((ushort)v[12][k]) + bf2f((ushort)v[13][k])) +
                             (bf2f((ushort)v[14][k]) + bf2f((ushort)v[15][k])));
            } else {
                int rc = m - 8;
                if (rc >= 4) {
#pragma unroll
                    for (int k = 0; k < 8; ++k)
                        a[k] += (bf2f((ushort)v[8][k]) + bf2f((ushort)v[9][k])) +
                                (bf2f((ushort)v[10][k]) + bf2f((ushort)v[11][k]));
                    if (rc > 4) {
#pragma unroll
                        for (int k = 0; k < 8; ++k) a[k] += bf2f((ushort)v[12][k]);
                    }
                    if (rc > 5) {
#pragma unroll
                        for (int k = 0; k < 8; ++k) a[k] += bf2f((ushort)v[13][k]);
                    }
                    if (rc > 6) {
#pragma unroll
                        for (int k = 0; k < 8; ++k) a[k] += bf2f((ushort)v[14][k]);
                    }
                } else {
                    if (rc > 0) {
#pragma unroll
                        for (int k = 0; k < 8; ++k) a[k] += bf2f((ushort)v[8][k]);
                    }
                    if (rc > 1) {
#pragma unroll
                        for (int k = 0; k < 8; ++k) a[k] += bf2f((ushort)v[9][k]);
                    }
                    if (rc > 2) {
#pragma unroll
                        for (int k = 0; k < 8; ++k) a[k] += bf2f((ushort)v[10][k]);
                    }
                }
            }
        } else {
            if (m >= 4) {
#pragma unroll
                for (int k = 0; k < 8; ++k)
                    a[k] += (bf2f((ushort)v[0][k]) + bf2f((ushort)v[1][k])) +
                            (bf2f((ushort)v[2][k]) + bf2f((ushort)v[3][k]));
                if (m > 4) {
#pragma unroll
                    for (int k = 0; k < 8; ++k) a[k] += bf2f((ushort)v[4][k]);
                }
                if (m > 5) {
#pragma unroll
                    for (int k = 0; k < 8; ++k) a[k] += bf2f((ushort)v[5][k]);
                }
                if (m > 6) {
#pragma unroll
                    for (int k = 0; k < 8; ++k) a[k] += bf2f((ushort)v[6][k]);
                }
            } else {
                if (m > 0) {
#pragma unroll
                    for (int k = 0; k < 8; ++k) a[k] += bf2f((ushort)v[0][k]);
                }
                if (m > 1) {
#pragma unroll
                    for (int k = 0; k < 8; ++k) a[k] += bf2f((ushort)v[1][k]);
                }
                if (m > 2) {
#pragma unroll
                    for (int k = 0; k < 8; ++k) a[k] += bf2f((ushort)v[2][k]);
                }
            }
        }
    }

    float inv = 1.0f / (float)(deg > 1 ? deg : 1);
    short8 yv = *(const short8*)(yb + (size_t)node * H + sl * 8);
    float4 bva = *(const float4*)(bl + sl * 8);
    float4 bvb = *(const float4*)(bl + sl * 8 + 4);
    float vv[8];
    vv[0] = a[0] * inv + bva.x + bf2f((ushort)yv[0]);
    vv[1] = a[1] * inv + bva.y + bf2f((ushort)yv[1]);
    vv[2] = a[2] * inv + bva.z + bf2f((ushort)yv[2]);
    vv[3] = a[3] * inv + bva.w + bf2f((ushort)yv[3]);
    vv[4] = a[4] * inv + bvb.x + bf2f((ushort)yv[4]);
    vv[5] = a[5] * inv + bvb.y + bf2f((ushort)yv[5]);
    vv[6] = a[6] * inv + bvb.z + bf2f((ushort)yv[6]);
    vv[7] = a[7] * inv + bvb.w + bf2f((ushort)yv[7]);
    if (norm) {
        float ss = 0.f;
#pragma unroll
        for (int k = 0; k < 8; ++k) ss += vv[k] * vv[k];
#pragma unroll
        for (int mm = 1; mm < 16; mm <<= 1) ss += __shfl_xor(ss, mm, 16);
        float n2 = 1.0f / fmaxf(sqrtf(ss), 1e-12f);
#pragma unroll
        for (int k = 0; k < 8; ++k) vv[k] *= n2;
    }
    short8 ho, lo8;
#pragma unroll
    for (int k = 0; k < 8; ++k) {
        ushort hh = f2bf(vv[k]);
        ho[k]  = (short)hh;
        lo8[k] = (short)f2bf(vv[k] - bf2f(hh));
    }
    *(short8*)(hhi + (size_t)node * H + sl * 8) = ho;
    *(short8*)(hlo + (size_t)node * H + sl * 8) = lo8;
}

// ---------------- global add pool (batch sorted), h = hi + lo ----------------

constexpr int POOL_ROWS = 64;

__global__ void k_pool(const ushort* __restrict__ hhi, const ushort* __restrict__ hlo,
                       const int* __restrict__ batch, float* __restrict__ g) {
    int col = threadIdx.x;  // 0..127
    int r0 = blockIdx.x * POOL_ROWS;
    int r1 = r0 + POOL_ROWS;
    if (r1 > N_NODES) r1 = N_NODES;
    if (r0 >= N_NODES) return;
    float acc = 0.f;
    int cur = batch[r0];
    int r = r0;
    for (; r + 4 <= r1; r += 4) {
        float v0 = bf2f(hhi[(size_t)r * H + col])       + bf2f(hlo[(size_t)r * H + col]);
        float v1 = bf2f(hhi[(size_t)(r + 1) * H + col]) + bf2f(hlo[(size_t)(r + 1) * H + col]);
        float v2 = bf2f(hhi[(size_t)(r + 2) * H + col]) + bf2f(hlo[(size_t)(r + 2) * H + col]);
        float v3 = bf2f(hhi[(size_t)(r + 3) * H + col]) + bf2f(hlo[(size_t)(r + 3) * H + col]);
        int b3 = batch[r + 3];
        if (b3 == cur) {
            acc += (v0 + v1) + (v2 + v3);
        } else {
            int b0 = batch[r], b1 = batch[r + 1], b2 = batch[r + 2];
            if (b0 != cur) { atomicAdd(&g[cur * H + col], acc); acc = 0.f; cur = b0; }
            acc += v0;
            if (b1 != cur) { atomicAdd(&g[cur * H + col], acc); acc = 0.f; cur = b1; }
            acc += v1;
            if (b2 != cur) { atomicAdd(&g[cur * H + col], acc); acc = 0.f; cur = b2; }
            acc += v2;
            if (b3 != cur) { atomicAdd(&g[cur * H + col], acc); acc = 0.f; cur = b3; }
            acc += v3;
        }
    }
    for (; r < r1; ++r) {
        int b = batch[r];
        if (b != cur) { atomicAdd(&g[cur * H + col], acc); acc = 0.f; cur = b; }
        acc += bf2f(hhi[(size_t)r * H + col]) + bf2f(hlo[(size_t)r * H + col]);
    }
    atomicAdd(&g[cur * H + col], acc);
}

// ---------------- MLP head ----------------

__global__ void k_mlp(const float* __restrict__ g, const float* __restrict__ W0,
                      const float* __restrict__ b0, const float* __restrict__ W1,
                      const float* __restrict__ b1, const float* __restrict__ Wh,
                      const float* __restrict__ bh, float* __restrict__ out) {
    int gi = blockIdx.x;
    int t  = threadIdx.x;  // 0..127
    __shared__ float buf0[H];
    __shared__ float buf1[H];
    __shared__ float red[2];

    float acc = b0[t];
    for (int k = 0; k < H; ++k) acc += g[gi * H + k] * W0[k * H + t];
    buf0[t] = fmaxf(acc, 0.f);
    __syncthreads();

    acc = b1[t];
    for (int k = 0; k < H; ++k) acc += buf0[k] * W1[k * H + t];
    buf1[t] = fmaxf(acc, 0.f);
    __syncthreads();

    float p = buf1[t] * Wh[t];
    for (int m = 1; m < 64; m <<= 1) p += __shfl_xor(p, m, 64);
    if ((t & 63) == 0) red[t >> 6] = p;
    __syncthreads();
    if (t == 0) out[gi] = red[0] + red[1] + bh[0];
}

// ---------------- driver ----------------

extern "C" void kernel_launch(void* const* d_in, const int* in_sizes, int n_in,
                              void* d_out, int out_size, void* d_ws, size_t ws_size,
                              hipStream_t stream) {
    const float* x     = (const float*)d_in[0];
    const int*   eic   = (const int*)d_in[1];
    const int*   eid   = (const int*)d_in[2];
    const int*   eit   = (const int*)d_in[3];
    const int*   batch = (const int*)d_in[4];
    const float* cW[5][3];
    for (int c = 0; c < 5; ++c) {
        cW[c][0] = (const float*)d_in[5 + c * 3 + 0];  // Wl
        cW[c][1] = (const float*)d_in[5 + c * 3 + 1];  // bl
        cW[c][2] = (const float*)d_in[5 + c * 3 + 2];  // Wr
    }
    const float* l0_W = (const float*)d_in[20];
    const float* l0_b = (const float*)d_in[21];
    const float* l1_W = (const float*)d_in[22];
    const float* l1_b = (const float*)d_in[23];
    const float* hd_W = (const float*)d_in[24];
    const float* hd_b = (const float*)d_in[25];
    float* outp = (float*)d_out;

    const size_t NH = (size_t)N_NODES * H;
    ushort* Ahi = (ushort*)d_ws;
    ushort* Alo = Ahi + NH;
    ushort* zb  = Alo + NH;
    ushort* yb  = zb + NH;
    ushort* Bpk = yb + NH;                     // 5 convs x 2 planes x 32768
    float*  gbuf = (float*)(Bpk + 5 * 2 * 32768);
    int* gcnt = (int*)(gbuf + (size_t)NG * H);     // zeroed by k_prep
    int* rcnt = gcnt + NB;                         // zeroed by k_prep
    int* ptr_all = rcnt + NB;                      // N3+1 ints (persistent)
    int* adj_all = ptr_all + (N3 + 1);             // 3*NE ints (persistent)
    // CSR-build scratch inside zb+yb (dead until first gemm, stream-ordered):
    //   bucket[NB*CAP2 int2] (64B-aligned at zb)  = 22.88 MB < zb+yb (25.6MB)
    int2* bucket = (int2*)zb;

    dim3 b256(256);

    // merged prep: weight pre-scatter (blocks<640) + x split + zeroing
    k_prep<<<dim3(640 + (int)(NH / 1024)), b256, 0, stream>>>(
        x, Ahi, Alo, (int*)gbuf,
        cW[0][0], cW[0][2], cW[1][0], cW[1][2], cW[2][0], cW[2][2],
        cW[3][0], cW[3][2], cW[4][0], cW[4][2], Bpk);

    // CSR build: bucketize -> per-bucket (total-scan + ptr + scatter)
    k_bucketize<<<dim3(3 * BPS), b256, 0, stream>>>(eic, eid, eit, gcnt, rcnt, bucket);
    k_scatter2<<<dim3(NB), dim3(512), 0, stream>>>(bucket, gcnt, rcnt, ptr_all, adj_all);

    const int L_set[7]  = {1, 0, 0, 2, 1, 0, 0};
    const int L_conv[7] = {0, 1, 1, 2, 3, 4, 4};
    const int L_norm[7] = {1, 1, 1, 0, 1, 1, 1};

    dim3 gAgg((N_NODES * 16 + 255) / 256);   // 16 lanes/node -> 3125 blocks
    dim3 gGemm((N_NODES + 63) / 64);         // 782

    for (int L = 0; L < 7; ++L) {
        int s = L_set[L], c = L_conv[L];
        const ushort* Bh = Bpk + (size_t)c * 65536;
        const ushort* Bl = Bh + 32768;
        k_gemm_mfma<<<gGemm, b256, 0, stream>>>(Ahi, Alo, Bh, Bl, zb, yb);
        k_aggnorm<<<gAgg, b256, 0, stream>>>(zb, yb, ptr_all + s * N_NODES, adj_all,
                                             cW[c][1], Ahi, Alo, L_norm[L]);
    }

    k_pool<<<dim3((N_NODES + POOL_ROWS - 1) / POOL_ROWS), dim3(H), 0, stream>>>(
        Ahi, Alo, batch, gbuf);
    k_mlp<<<dim3(NG), dim3(H), 0, stream>>>(gbuf, l0_W, l0_b, l1_W, l1_b, hd_W, hd_b,
                                            outp);
}

// Round 6
// 509.742 us; speedup vs baseline: 1.3782x; 1.0128x over previous
//
#include <hip/hip_runtime.h>
#include <hip/hip_bf16.h>

// ValueNet: 7x SAGEConv(mean) + global_add_pool + MLP head.
// N=50000 nodes, E=600000 edges/set, H=128, G=64 graphs.
//
// out_i = mean_j(z_j) + bl + y_i,  z = h@Wl, y = h@Wr (linearity of mean).
// GEMM on MFMA bf16 with split precision (hi+lo planes, 3 MFMAs: hh+hl+lh).
// z,y stored bf16. h stored as hi/lo bf16 planes.
//
// R18: aggnorm occupancy experiment. R13/R16/R17 showed the gather is not
//      instruction-, L2-residency-, or ILP-bound; remaining theory is wave
//      concurrency (R17's v[16] = 64 VGPR for the buffer alone -> ~4
//      waves/SIMD). Now: 8 loads in flight (v[8], two halves per 16-edge
//      adj fetch) + __launch_bounds__(256,8) forcing <=64 VGPR -> 8
//      waves/SIMD. Accumulation tree replicated bit-for-bit from R13/R17.
// R17: k_prep = merged wsplit+split+zeroing.
// R14: GEMM A-staging via global_load_lds(16B), XOR-swizzled source;
//      k_scatter2 at 512 threads.
// CSR build (R12): LDS-staged bucket sort, NO per-key global atomics.

constexpr int N_NODES = 50000;
constexpr int NE      = 600000;
constexpr int H       = 128;
constexpr int NG      = 64;
constexpr int N3      = 3 * N_NODES;            // 150000

constexpr int NB   = (N3 + 1023) >> 10;          // 147 buckets (1024 keys each)
constexpr int EPB  = 2048;                       // edges per block (phase A)
constexpr int BPS  = (NE + EPB - 1) / EPB;       // 293 blocks per edge set
constexpr int CAP2 = 19456;                      // slots/bucket (exp ~15.4k padded; mult of 8)

typedef __attribute__((ext_vector_type(8))) short short8;
typedef __attribute__((ext_vector_type(4))) float f32x4;

__device__ __forceinline__ ushort f2bf(float f) {  // RNE float->bf16
    uint x = __float_as_uint(f);
    return (ushort)((x + 0x7FFFu + ((x >> 16) & 1u)) >> 16);
}
__device__ __forceinline__ float bf2f(ushort u) {
    return __uint_as_float(((uint)u) << 16);
}

// ---------------- Phase A: LDS-staged bucketize (padded, sentinel-filled) ----------------

__global__ __launch_bounds__(256) void k_bucketize(
    const int* __restrict__ e0, const int* __restrict__ e1,
    const int* __restrict__ e2, int* __restrict__ gcnt,
    int* __restrict__ rcnt, int2* __restrict__ bucket) {
    __shared__ int hist[NB];
    __shared__ int basearr[NB];
    __shared__ int cur[NB];
    __shared__ int gposs[NB];
    __shared__ int2 stage[EPB];
    __shared__ int dstoff[EPB];

    int t = threadIdx.x;
    int s = blockIdx.x / BPS;
    int w = blockIdx.x - s * BPS;
    const int* ep = (s == 0 ? e0 : (s == 1 ? e1 : e2));
    int eBase = w * EPB;
    int m = NE - eBase;
    if (m > EPB) m = EPB;

    for (int i = t; i < NB; i += 256) hist[i] = 0;
    __syncthreads();

    // pass 1: read edges into regs, LDS histogram
    int myk[EPB / 256], mys[EPB / 256];
#pragma unroll
    for (int k = 0; k < EPB / 256; ++k) {
        int i = t + 256 * k;
        if (i < m) {
            int d   = ep[NE + eBase + i];
            int src = ep[eBase + i];
            int key = s * N_NODES + d;
            myk[k] = key; mys[k] = src;
            atomicAdd(&hist[key >> 10], 1);
        } else {
            myk[k] = -1;
        }
    }
    __syncthreads();

    if (t == 0) {  // serial scan over 147 entries (cheap)
        int run = 0;
        for (int b = 0; b < NB; ++b) { basearr[b] = run; run += hist[b]; }
    }
    __syncthreads();

    if (t < NB) {  // padded reserve: ONE atomic per (block,bucket); runs 64B-aligned
        int h = hist[t];
        int p = (h + 7) & ~7;
        gposs[t] = p ? atomicAdd(&gcnt[t], p) : 0;
        if (h) atomicAdd(&rcnt[t], h);
        cur[t] = 0;
    }
    __syncthreads();

    // pass 2: scatter into LDS stage in bucket order; record dense dst offsets
#pragma unroll
    for (int k = 0; k < EPB / 256; ++k) {
        if (myk[k] >= 0) {
            int b  = myk[k] >> 10;
            int sl = atomicAdd(&cur[b], 1);
            int p  = basearr[b] + sl;
            stage[p]  = make_int2(myk[k], mys[k]);
            dstoff[p] = b * CAP2 + gposs[b] + sl;
        }
    }
    __syncthreads();

    // copyout: consecutive stage slots within a run -> consecutive global addrs
    for (int i = t; i < m; i += 256) bucket[dstoff[i]] = stage[i];
    // sentinel-fill the pad slots (<=7 per (block,bucket), same lines as runs)
    for (int i = t; i < NB * 8; i += 256) {
        int b = i >> 3, j = i & 7;
        int h = hist[b];
        int p = (h + 7) & ~7;
        if (h + j < p)
            bucket[(size_t)b * CAP2 + gposs[b] + h + j] = make_int2(-1, 0);
    }
}

// ---------------- Phase B: per-bucket hist + scan -> ptr slice + adj scatter ----------------

__global__ __launch_bounds__(512) void k_scatter2(const int2* __restrict__ bucket,
                                                  const int* __restrict__ gcnt,
                                                  const int* __restrict__ rcnt,
                                                  int* __restrict__ ptr,
                                                  int* __restrict__ adj) {
    int b = blockIdx.x;           // 0..NB-1
    int base = b << 10;
    int nk = N3 - base;
    if (nk > 1024) nk = 1024;
    __shared__ int lh[1024];
    __shared__ int lsum[512];
    __shared__ int lfill[1024];
    __shared__ int bb;
    int t = threadIdx.x;

    // exclusive prefix of real bucket totals -> bb (value at index b only)
    int rv = (t < NB) ? rcnt[t] : 0;
    lsum[t] = rv;
    __syncthreads();
    for (int off = 1; off < 512; off <<= 1) {
        int u = (t >= off) ? lsum[t - off] : 0;
        __syncthreads();
        if (t >= off) lsum[t] += u;
        __syncthreads();
    }
    if (t == b) bb = lsum[t] - rv;
    if (b == 0 && t == 0) ptr[N3] = 3 * NE;
    for (int i = t; i < 1024; i += 512) lh[i] = 0;
    __syncthreads();

    int c = gcnt[b];              // padded slot count actually used
    const int2* seg = bucket + (size_t)b * CAP2;
    for (int i = t; i < c; i += 512) {
        int k = seg[i].x;
        if (k >= 0) atomicAdd(&lh[k - base], 1);
    }
    __syncthreads();
    // exclusive 1024-scan: 2 seq per thread + 512 Hillis-Steele
    int v0 = lh[t * 2], v1 = lh[t * 2 + 1];
    int ts = v0 + v1;
    lsum[t] = ts;
    __syncthreads();
    for (int off = 1; off < 512; off <<= 1) {
        int u = (t >= off) ? lsum[t - off] : 0;
        __syncthreads();
        if (t >= off) lsum[t] += u;
        __syncthreads();
    }
    int ex = lsum[t] - ts + bb;
    int e0 = ex, e1 = ex + v0;
    if (t * 2     < nk) { ptr[base + t * 2]     = e0; lfill[t * 2]     = e0; }
    if (t * 2 + 1 < nk) { ptr[base + t * 2 + 1] = e1; lfill[t * 2 + 1] = e1; }
    __syncthreads();
    for (int i = t; i < c; i += 512) {
        int2 ed = seg[i];
        if (ed.x >= 0) {
            int pos = atomicAdd(&lfill[ed.x - base], 1);
            adj[pos] = ed.y;
        }
    }
}

// ---------------- R17: merged prep = weight pre-scatter + x split + zeroing ----------------

__global__ void k_prep(const float* __restrict__ x, ushort* __restrict__ hi,
                       ushort* __restrict__ lo, int* __restrict__ zmem,
                       const float* W0l, const float* W0r, const float* W1l,
                       const float* W1r, const float* W2l, const float* W2r,
                       const float* W3l, const float* W3r, const float* W4l,
                       const float* W4r, ushort* __restrict__ Bpk) {
    int bid = blockIdx.x;
    int t   = threadIdx.x;
    if (bid < 640) {
        int idx = bid * 256 + t;  // 0..5*32768-1
        if (idx >= 5 * 32768) return;
        int c = idx >> 15, r = idx & 32767;
        const float* Wl = (c == 0 ? W0l : c == 1 ? W1l : c == 2 ? W2l : c == 3 ? W3l : W4l);
        const float* Wr = (c == 0 ? W0r : c == 1 ? W1r : c == 2 ? W2r : c == 3 ? W3r : W4r);
        int n = r & 255, k = r >> 8;
        float w = (n < H) ? Wl[k * H + n] : Wr[k * H + (n - H)];
        int q = k >> 5, g = (k >> 3) & 3, j = k & 7;
        int off = ((q * 4 + g) * 256 + n) * 8 + j;
        ushort h = f2bf(w);
        ushort* bh = Bpk + (size_t)c * 65536;
        bh[off]         = h;
        bh[32768 + off] = f2bf(w - bf2f(h));
        return;
    }
    int tid = (bid - 640) * 256 + t;
    if (tid < NG * H + 2 * NB) zmem[tid] = 0;   // gbuf + gcnt + rcnt
    size_t i = (size_t)tid * 4;
    if (i >= (size_t)N_NODES * H) return;
    float4 v = *(const float4*)(x + i);
    ushort4 h, l;
    h.x = f2bf(v.x); l.x = f2bf(v.x - bf2f(h.x));
    h.y = f2bf(v.y); l.y = f2bf(v.y - bf2f(h.y));
    h.z = f2bf(v.z); l.z = f2bf(v.z - bf2f(h.z));
    h.w = f2bf(v.w); l.w = f2bf(v.w - bf2f(h.w));
    *(ushort4*)(hi + i) = h;
    *(ushort4*)(lo + i) = l;
}

// ---------------- MFMA GEMM: (z,y) = (Ahi+Alo) @ (Bhi+Blo) ----------------
// R14 staging: global_load_lds(16B), linear LDS dest, XOR-swizzled source.

__global__ __launch_bounds__(256) void k_gemm_mfma(
    const ushort* __restrict__ Ahi, const ushort* __restrict__ Alo,
    const ushort* __restrict__ Bh, const ushort* __restrict__ Bl,
    ushort* __restrict__ z, ushort* __restrict__ yb) {
    __shared__ ushort AshF[2 * 64 * 128];   // 32 KB
    int t = threadIdx.x;
    int rowBase = blockIdx.x * 64;
    {
        int wslot = t & ~63;                 // wave-uniform slot base
        int lane  = t & 63;
#pragma unroll
        for (int i = 0; i < 8; ++i) {
            int sbase = i * 256 + wslot;     // wave's first slot this round
            int S     = sbase + lane;        // this lane's slot
            int plane = S >> 10;
            int row   = (S >> 4) & 63;
            int pc    = S & 15;
            int grow  = rowBase + row;
            if (grow > N_NODES - 1) grow = N_NODES - 1;
            const ushort* Ap  = plane ? Alo : Ahi;
            const ushort* src = Ap + (size_t)grow * H + ((pc ^ (row & 15)) << 3);
            ushort* ldst = AshF + (size_t)sbase * 8;   // wave-uniform; HW adds lane*16B
            __builtin_amdgcn_global_load_lds(
                (const __attribute__((address_space(1))) void*)src,
                (__attribute__((address_space(3))) void*)ldst, 16, 0, 0);
        }
    }
    __syncthreads();

    int wave = t >> 6, lane = t & 63;
    int m16 = lane & 15, q4 = lane >> 4;
    int n0 = wave * 64;

    f32x4 acc[4][4];
#pragma unroll
    for (int r = 0; r < 4; ++r)
#pragma unroll
        for (int c = 0; c < 4; ++c) {
            acc[r][c][0] = 0.f; acc[r][c][1] = 0.f;
            acc[r][c][2] = 0.f; acc[r][c][3] = 0.f;
        }

    for (int q = 0; q < 4; ++q) {
        short8 bh_[4], bl_[4], ah_[4], al_[4];
#pragma unroll
        for (int c = 0; c < 4; ++c) {
            int boff = ((q * 4 + q4) * 256 + n0 + c * 16 + m16) * 8;
            bh_[c] = *(const short8*)(Bh + boff);
            bl_[c] = *(const short8*)(Bl + boff);
        }
#pragma unroll
        for (int r = 0; r < 4; ++r) {
            int roff = ((r * 16 + m16) << 7) + (((q * 4 + q4) ^ m16) << 3);
            ah_[r] = *(const short8*)&AshF[roff];
            al_[r] = *(const short8*)&AshF[8192 + roff];
        }
#pragma unroll
        for (int r = 0; r < 4; ++r)
#pragma unroll
            for (int c = 0; c < 4; ++c) {
                acc[r][c] = __builtin_amdgcn_mfma_f32_16x16x32_bf16(
                    ah_[r], bh_[c], acc[r][c], 0, 0, 0);
                acc[r][c] = __builtin_amdgcn_mfma_f32_16x16x32_bf16(
                    ah_[r], bl_[c], acc[r][c], 0, 0, 0);
                acc[r][c] = __builtin_amdgcn_mfma_f32_16x16x32_bf16(
                    al_[r], bh_[c], acc[r][c], 0, 0, 0);
            }
    }

    // C/D layout: col=lane&15, row=(lane>>4)*4+reg (m89-verified)
#pragma unroll
    for (int r = 0; r < 4; ++r)
#pragma unroll
        for (int c = 0; c < 4; ++c) {
            int col = n0 + c * 16 + m16;
            ushort* op = (col < H) ? (z + col) : (yb + (col - H));
#pragma unroll
            for (int j = 0; j < 4; ++j) {
                int gr = rowBase + r * 16 + q4 * 4 + j;
                if (gr < N_NODES) op[(size_t)gr * H] = f2bf(acc[r][c][j]);
            }
        }
}

// ---------------- R18 gather + epilogue: 8-in-flight halves, 8 waves/SIMD ----------------
// 16 lanes/node; adj fetched once per 16 edges; two 8-load halves reuse the
// same v[8] buffer (32 VGPR). Accumulation tree replicates R13/R17 exactly.

__global__ __launch_bounds__(256, 8) void k_aggnorm(
    const ushort* __restrict__ z, const ushort* __restrict__ yb,
    const int* __restrict__ ptr, const int* __restrict__ adj,
    const float* __restrict__ bl,
    ushort* __restrict__ hhi, ushort* __restrict__ hlo, int norm) {
    int gtid = blockIdx.x * blockDim.x + threadIdx.x;
    int node = gtid >> 4;                  // 16 lanes per node
    int sl   = threadIdx.x & 15;           // lane covers cols [sl*8, sl*8+8)
    if (node >= N_NODES) return;
    int beg = ptr[node], end = ptr[node + 1];
    int deg = end - beg;
    const ushort* zrow = z + sl * 8;
    float a[8];
#pragma unroll
    for (int k = 0; k < 8; ++k) a[k] = 0.f;

    for (int base = 0; base < deg; base += 16) {
        int m = deg - base;
        if (m > 16) m = 16;
        int idx = (sl < m) ? adj[beg + base + sl] : 0;
#pragma unroll
        for (int half = 0; half < 2; ++half) {
            int mh = m - half * 8;
            if (mh <= 0) continue;
            if (mh > 8) mh = 8;
            int hb = half * 8;
            short8 v[8];
#pragma unroll
            for (int jj = 0; jj < 8; ++jj) {
                int nj = __shfl(idx, hb + jj, 16);
                if (jj < mh) v[jj] = *(const short8*)(zrow + (size_t)nj * H);
            }
            // ---- accumulation: EXACT replication of the 8/4/1 rounds ----
            if (mh == 8) {
#pragma unroll
                for (int k = 0; k < 8; ++k)
                    a[k] += ((bf2f((ushort)v[0][k]) + bf2f((ushort)v[1][k])) +
                             (bf2f((ushort)v[2][k]) + bf2f((ushort)v[3][k]))) +
                            ((bf2f((ushort)v[4][k]) + bf2f((ushort)v[5][k])) +
                             (bf2f((ushort)v[6][k]) + bf2f((ushort)v[7][k])));
            } else if (mh >= 4) {
#pragma unroll
                for (int k = 0; k < 8; ++k)
                    a[k] += (bf2f((ushort)v[0][k]) + bf2f((ushort)v[1][k])) +
                            (bf2f((ushort)v[2][k]) + bf2f((ushort)v[3][k]));
                if (mh > 4) {
#pragma unroll
                    for (int k = 0; k < 8; ++k) a[k] += bf2f((ushort)v[4][k]);
                }
                if (mh > 5) {
#pragma unroll
                    for (int k = 0; k < 8; ++k) a[k] += bf2f((ushort)v[5][k]);
                }
                if (mh > 6) {
#pragma unroll
                    for (int k = 0; k < 8; ++k) a[k] += bf2f((ushort)v[6][k]);
                }
            } else {
                if (mh > 0) {
#pragma unroll
                    for (int k = 0; k < 8; ++k) a[k] += bf2f((ushort)v[0][k]);
                }
                if (mh > 1) {
#pragma unroll
                    for (int k = 0; k < 8; ++k) a[k] += bf2f((ushort)v[1][k]);
                }
                if (mh > 2) {
#pragma unroll
                    for (int k = 0; k < 8; ++k) a[k] += bf2f((ushort)v[2][k]);
                }
            }
        }
    }

    float inv = 1.0f / (float)(deg > 1 ? deg : 1);
    short8 yv = *(const short8*)(yb + (size_t)node * H + sl * 8);
    float4 bva = *(const float4*)(bl + sl * 8);
    float4 bvb = *(const float4*)(bl + sl * 8 + 4);
    float vv[8];
    vv[0] = a[0] * inv + bva.x + bf2f((ushort)yv[0]);
    vv[1] = a[1] * inv + bva.y + bf2f((ushort)yv[1]);
    vv[2] = a[2] * inv + bva.z + bf2f((ushort)yv[2]);
    vv[3] = a[3] * inv + bva.w + bf2f((ushort)yv[3]);
    vv[4] = a[4] * inv + bvb.x + bf2f((ushort)yv[4]);
    vv[5] = a[5] * inv + bvb.y + bf2f((ushort)yv[5]);
    vv[6] = a[6] * inv + bvb.z + bf2f((ushort)yv[6]);
    vv[7] = a[7] * inv + bvb.w + bf2f((ushort)yv[7]);
    if (norm) {
        float ss = 0.f;
#pragma unroll
        for (int k = 0; k < 8; ++k) ss += vv[k] * vv[k];
#pragma unroll
        for (int mm = 1; mm < 16; mm <<= 1) ss += __shfl_xor(ss, mm, 16);
        float n2 = 1.0f / fmaxf(sqrtf(ss), 1e-12f);
#pragma unroll
        for (int k = 0; k < 8; ++k) vv[k] *= n2;
    }
    short8 ho, lo8;
#pragma unroll
    for (int k = 0; k < 8; ++k) {
        ushort hh = f2bf(vv[k]);
        ho[k]  = (short)hh;
        lo8[k] = (short)f2bf(vv[k] - bf2f(hh));
    }
    *(short8*)(hhi + (size_t)node * H + sl * 8) = ho;
    *(short8*)(hlo + (size_t)node * H + sl * 8) = lo8;
}

// ---------------- global add pool (batch sorted), h = hi + lo ----------------

constexpr int POOL_ROWS = 64;

__global__ void k_pool(const ushort* __restrict__ hhi, const ushort* __restrict__ hlo,
                       const int* __restrict__ batch, float* __restrict__ g) {
    int col = threadIdx.x;  // 0..127
    int r0 = blockIdx.x * POOL_ROWS;
    int r1 = r0 + POOL_ROWS;
    if (r1 > N_NODES) r1 = N_NODES;
    if (r0 >= N_NODES) return;
    float acc = 0.f;
    int cur = batch[r0];
    int r = r0;
    for (; r + 4 <= r1; r += 4) {
        float v0 = bf2f(hhi[(size_t)r * H + col])       + bf2f(hlo[(size_t)r * H + col]);
        float v1 = bf2f(hhi[(size_t)(r + 1) * H + col]) + bf2f(hlo[(size_t)(r + 1) * H + col]);
        float v2 = bf2f(hhi[(size_t)(r + 2) * H + col]) + bf2f(hlo[(size_t)(r + 2) * H + col]);
        float v3 = bf2f(hhi[(size_t)(r + 3) * H + col]) + bf2f(hlo[(size_t)(r + 3) * H + col]);
        int b3 = batch[r + 3];
        if (b3 == cur) {
            acc += (v0 + v1) + (v2 + v3);
        } else {
            int b0 = batch[r], b1 = batch[r + 1], b2 = batch[r + 2];
            if (b0 != cur) { atomicAdd(&g[cur * H + col], acc); acc = 0.f; cur = b0; }
            acc += v0;
            if (b1 != cur) { atomicAdd(&g[cur * H + col], acc); acc = 0.f; cur = b1; }
            acc += v1;
            if (b2 != cur) { atomicAdd(&g[cur * H + col], acc); acc = 0.f; cur = b2; }
            acc += v2;
            if (b3 != cur) { atomicAdd(&g[cur * H + col], acc); acc = 0.f; cur = b3; }
            acc += v3;
        }
    }
    for (; r < r1; ++r) {
        int b = batch[r];
        if (b != cur) { atomicAdd(&g[cur * H + col], acc); acc = 0.f; cur = b; }
        acc += bf2f(hhi[(size_t)r * H + col]) + bf2f(hlo[(size_t)r * H + col]);
    }
    atomicAdd(&g[cur * H + col], acc);
}

// ---------------- MLP head ----------------

__global__ void k_mlp(const float* __restrict__ g, const float* __restrict__ W0,
                      const float* __restrict__ b0, const float* __restrict__ W1,
                      const float* __restrict__ b1, const float* __restrict__ Wh,
                      const float* __restrict__ bh, float* __restrict__ out) {
    int gi = blockIdx.x;
    int t  = threadIdx.x;  // 0..127
    __shared__ float buf0[H];
    __shared__ float buf1[H];
    __shared__ float red[2];

    float acc = b0[t];
    for (int k = 0; k < H; ++k) acc += g[gi * H + k] * W0[k * H + t];
    buf0[t] = fmaxf(acc, 0.f);
    __syncthreads();

    acc = b1[t];
    for (int k = 0; k < H; ++k) acc += buf0[k] * W1[k * H + t];
    buf1[t] = fmaxf(acc, 0.f);
    __syncthreads();

    float p = buf1[t] * Wh[t];
    for (int m = 1; m < 64; m <<= 1) p += __shfl_xor(p, m, 64);
    if ((t & 63) == 0) red[t >> 6] = p;
    __syncthreads();
    if (t == 0) out[gi] = red[0] + red[1] + bh[0];
}

// ---------------- driver ----------------

extern "C" void kernel_launch(void* const* d_in, const int* in_sizes, int n_in,
                              void* d_out, int out_size, void* d_ws, size_t ws_size,
                              hipStream_t stream) {
    const float* x     = (const float*)d_in[0];
    const int*   eic   = (const int*)d_in[1];
    const int*   eid   = (const int*)d_in[2];
    const int*   eit   = (const int*)d_in[3];
    const int*   batch = (const int*)d_in[4];
    const float* cW[5][3];
    for (int c = 0; c < 5; ++c) {
        cW[c][0] = (const float*)d_in[5 + c * 3 + 0];  // Wl
        cW[c][1] = (const float*)d_in[5 + c * 3 + 1];  // bl
        cW[c][2] = (const float*)d_in[5 + c * 3 + 2];  // Wr
    }
    const float* l0_W = (const float*)d_in[20];
    const float* l0_b = (const float*)d_in[21];
    const float* l1_W = (const float*)d_in[22];
    const float* l1_b = (const float*)d_in[23];
    const float* hd_W = (const float*)d_in[24];
    const float* hd_b = (const float*)d_in[25];
    float* outp = (float*)d_out;

    const size_t NH = (size_t)N_NODES * H;
    ushort* Ahi = (ushort*)d_ws;
    ushort* Alo = Ahi + NH;
    ushort* zb  = Alo + NH;
    ushort* yb  = zb + NH;
    ushort* Bpk = yb + NH;                     // 5 convs x 2 planes x 32768
    float*  gbuf = (float*)(Bpk + 5 * 2 * 32768);
    int* gcnt = (int*)(gbuf + (size_t)NG * H);     // zeroed by k_prep
    int* rcnt = gcnt + NB;                         // zeroed by k_prep
    int* ptr_all = rcnt + NB;                      // N3+1 ints (persistent)
    int* adj_all = ptr_all + (N3 + 1);             // 3*NE ints (persistent)
    // CSR-build scratch inside zb+yb (dead until first gemm, stream-ordered):
    //   bucket[NB*CAP2 int2] (64B-aligned at zb)  = 22.88 MB < zb+yb (25.6MB)
    int2* bucket = (int2*)zb;

    dim3 b256(256);

    // merged prep: weight pre-scatter (blocks<640) + x split + zeroing
    k_prep<<<dim3(640 + (int)(NH / 1024)), b256, 0, stream>>>(
        x, Ahi, Alo, (int*)gbuf,
        cW[0][0], cW[0][2], cW[1][0], cW[1][2], cW[2][0], cW[2][2],
        cW[3][0], cW[3][2], cW[4][0], cW[4][2], Bpk);

    // CSR build: bucketize -> per-bucket (total-scan + ptr + scatter)
    k_bucketize<<<dim3(3 * BPS), b256, 0, stream>>>(eic, eid, eit, gcnt, rcnt, bucket);
    k_scatter2<<<dim3(NB), dim3(512), 0, stream>>>(bucket, gcnt, rcnt, ptr_all, adj_all);

    const int L_set[7]  = {1, 0, 0, 2, 1, 0, 0};
    const int L_conv[7] = {0, 1, 1, 2, 3, 4, 4};
    const int L_norm[7] = {1, 1, 1, 0, 1, 1, 1};

    dim3 gAgg((N_NODES * 16 + 255) / 256);   // 16 lanes/node -> 3125 blocks
    dim3 gGemm((N_NODES + 63) / 64);         // 782

    for (int L = 0; L < 7; ++L) {
        int s = L_set[L], c = L_conv[L];
        const ushort* Bh = Bpk + (size_t)c * 65536;
        const ushort* Bl = Bh + 32768;
        k_gemm_mfma<<<gGemm, b256, 0, stream>>>(Ahi, Alo, Bh, Bl, zb, yb);
        k_aggnorm<<<gAgg, b256, 0, stream>>>(zb, yb, ptr_all + s * N_NODES, adj_all,
                                             cW[c][1], Ahi, Alo, L_norm[L]);
    }

    k_pool<<<dim3((N_NODES + POOL_ROWS - 1) / POOL_ROWS), dim3(H), 0, stream>>>(
        Ahi, Alo, batch, gbuf);
    k_mlp<<<dim3(NG), dim3(H), 0, stream>>>(gbuf, l0_W, l0_b, l1_W, l1_b, hd_W, hd_b,
                                            outp);
}